// Round 1
// baseline (12452.019 us; speedup 1.0000x reference)
//
#include <hip/hip_runtime.h>

#define HD 128      // hidden dim
#define HV 32       // float4 per row
#define TS 16       // rows per GEMM tile
#define ASTR 132    // padded A-tile stride (floats)

// ---------------- elementwise / scatter kernels ----------------

__global__ __launch_bounds__(256) void k_counts(const int* __restrict__ node_ids,
        float* __restrict__ cnt_node, float* __restrict__ cnt_root,
        float* __restrict__ vf, int SK) {
    int i = blockIdx.x * blockDim.x + threadIdx.x;
    if (i >= SK) return;
    int id = node_ids[i];
    vf[i] = (id >= 0) ? 1.0f : 0.0f;
    if (id >= 0) {
        atomicAdd(&cnt_node[id], 1.0f);
        if ((i & 15) == 0) atomicAdd(&cnt_root[id], 1.0f);  // root rows: i % k_sub == 0
    }
}

__global__ __launch_bounds__(256) void k_init_h(const float* __restrict__ at,
        const float* __restrict__ rt, const int* __restrict__ atom_ids,
        const float* __restrict__ vf, float* __restrict__ h, int SK) {
    int t = blockIdx.x * blockDim.x + threadIdx.x;
    int i = t >> 5, c = t & 31;
    if (i >= SK) return;
    float4 a = ((const float4*)at)[(size_t)atom_ids[i] * HV + c];
    int role = ((i & 15) == 0) ? 1 : 0;
    float4 r = ((const float4*)rt)[role * HV + c];
    float m = vf[i];
    float4 v;
    v.x = (a.x + r.x) * m; v.y = (a.y + r.y) * m;
    v.z = (a.z + r.z) * m; v.w = (a.w + r.w) * m;
    ((float4*)h)[(size_t)i * HV + c] = v;
}

// out[dst[e]] += relu(X[src[e]] + btab[bids[e]])   (atomic)
__global__ __launch_bounds__(256) void k_scatter_edges(const float* __restrict__ X,
        const int* __restrict__ src, const int* __restrict__ dst,
        const int* __restrict__ bids, const float* __restrict__ btab,
        float* __restrict__ out, int E) {
    int t = blockIdx.x * blockDim.x + threadIdx.x;
    int e = t >> 5, c = t & 31;
    if (e >= E) return;
    int s = src[e], d = dst[e];
    float4 x = ((const float4*)X)[(size_t)s * HV + c];
    float4 b = ((const float4*)btab)[(size_t)bids[e] * HV + c];
    float4 m;
    m.x = fmaxf(x.x + b.x, 0.0f); m.y = fmaxf(x.y + b.y, 0.0f);
    m.z = fmaxf(x.z + b.z, 0.0f); m.w = fmaxf(x.w + b.w, 0.0f);
    float* o = out + (size_t)d * HD + c * 4;
    atomicAdd(o + 0, m.x); atomicAdd(o + 1, m.y);
    atomicAdd(o + 2, m.z); atomicAdd(o + 3, m.w);
}

// out[ids[i*stride]] += X[i*stride]  for valid ids (segment-sum numerator)
__global__ __launch_bounds__(256) void k_scatter_rows(const float* __restrict__ X,
        const int* __restrict__ ids, float* __restrict__ out, int M, int stride) {
    int t = blockIdx.x * blockDim.x + threadIdx.x;
    int i = t >> 5, c = t & 31;
    if (i >= M) return;
    int row = i * stride;
    int id = ids[row];
    if (id < 0) return;
    float4 x = ((const float4*)X)[(size_t)row * HV + c];
    float* o = out + (size_t)id * HD + c * 4;
    atomicAdd(o + 0, x.x); atomicAdd(o + 1, x.y);
    atomicAdd(o + 2, x.z); atomicAdd(o + 3, x.w);
}

__global__ __launch_bounds__(256) void k_divide(float* __restrict__ buf,
        const float* __restrict__ cnt, int N) {
    int t = blockIdx.x * blockDim.x + threadIdx.x;
    int n = t >> 5, c = t & 31;
    if (n >= N) return;
    float inv = 1.0f / fmaxf(cnt[n], 1.0f);
    float4* p = &((float4*)buf)[(size_t)n * HV + c];
    float4 v = *p;
    v.x *= inv; v.y *= inv; v.z *= inv; v.w *= inv;
    *p = v;
}

// acc[i] += src[max(idx[i],0)] * vf[i]
__global__ __launch_bounds__(256) void k_gather_add(float* __restrict__ acc,
        const float* __restrict__ src, const int* __restrict__ idx,
        const float* __restrict__ vf, int M) {
    int t = blockIdx.x * blockDim.x + threadIdx.x;
    int i = t >> 5, c = t & 31;
    if (i >= M) return;
    int id = idx[i]; id = (id > 0) ? id : 0;
    float m = vf[i];
    float4 s = ((const float4*)src)[(size_t)id * HV + c];
    float4* a = &((float4*)acc)[(size_t)i * HV + c];
    float4 v = *a;
    v.x += s.x * m; v.y += s.y * m; v.z += s.z * m; v.w += s.w * m;
    *a = v;
}

// h[i] = relu(t[i]) * vf[i]
__global__ __launch_bounds__(256) void k_relu_mask(float* __restrict__ h,
        const float* __restrict__ tin, const float* __restrict__ vf, int M) {
    int t = blockIdx.x * blockDim.x + threadIdx.x;
    int i = t >> 5, c = t & 31;
    if (i >= M) return;
    float m = vf[i];
    float4 v = ((const float4*)tin)[(size_t)i * HV + c];
    v.x = fmaxf(v.x, 0.0f) * m; v.y = fmaxf(v.y, 0.0f) * m;
    v.z = fmaxf(v.z, 0.0f) * m; v.w = fmaxf(v.w, 0.0f) * m;
    ((float4*)h)[(size_t)i * HV + c] = v;
}

// out[batch[n]] += xsum[n]   (global_add_pool)
__global__ __launch_bounds__(256) void k_pool(const float* __restrict__ xsum,
        const int* __restrict__ batch, float* __restrict__ out, int N) {
    int t = blockIdx.x * blockDim.x + threadIdx.x;
    int n = t >> 5, c = t & 31;
    if (n >= N) return;
    int g = batch[n];
    float4 x = ((const float4*)xsum)[(size_t)n * HV + c];
    float* o = out + (size_t)g * HD + c * 4;
    atomicAdd(o + 0, x.x); atomicAdd(o + 1, x.y);
    atomicAdd(o + 2, x.z); atomicAdd(o + 3, x.w);
}

// ---------------- 128x128 GEMM: C = epi((A[gather] + A2) @ W^T + b) ----------------
// gmode: 0 = identity, 1 = A row = max(gidx[row],0), 2 = A row = row & ~15
// epilogue: y = y*scale + shift (if scale); relu (if relu_flag); *vf[row] (if vf);
//           C[row] (+)= y  (acc_flag)
// W staged transposed in LDS in two 64-col halves (32 KB each) -> 40 KB LDS total.
__global__ __launch_bounds__(256) void k_gemm128(
        const float* __restrict__ A, const float* __restrict__ A2,
        const int* __restrict__ gidx, int gmode,
        const float* __restrict__ W, const float* __restrict__ bias,
        const float* __restrict__ scale, const float* __restrict__ shift,
        const float* __restrict__ vf, float* __restrict__ C,
        int M, int relu_flag, int acc_flag) {
    __shared__ float Wt[HD * 64];    // Wt[k*64 + jl] = W[(half*64+jl)*128 + k]
    __shared__ float As[TS * ASTR];  // padded to avoid 4-way broadcast conflicts
    const int t = threadIdx.x;
    const int r = t >> 4;   // 0..15 (row within tile)
    const int c = t & 15;   // 0..15 (4-col group within 64-col half)
    const int ntiles = (M + TS - 1) / TS;
    for (int half = 0; half < 2; ++half) {
        __syncthreads();
        for (int idx = t; idx < HD * 64; idx += 256) {
            int jl = idx >> 7, k = idx & 127;
            Wt[k * 64 + jl] = W[(size_t)(half * 64 + jl) * HD + k];
        }
        __syncthreads();
        float4 b4 = ((const float4*)bias)[half * 16 + c];
        float4 s4 = make_float4(1.f, 1.f, 1.f, 1.f);
        float4 sh4 = make_float4(0.f, 0.f, 0.f, 0.f);
        if (scale) {
            s4 = ((const float4*)scale)[half * 16 + c];
            sh4 = ((const float4*)shift)[half * 16 + c];
        }
        for (int tile = blockIdx.x; tile < ntiles; tile += gridDim.x) {
            int row0 = tile * TS;
            __syncthreads();
            for (int idx = t; idx < TS * HD; idx += 256) {
                int rr = idx >> 7, kk = idx & 127;
                int row = row0 + rr;
                float v = 0.0f;
                if (row < M) {
                    int arow = row;
                    if (gmode == 1) { int g = gidx[row]; arow = (g > 0) ? g : 0; }
                    else if (gmode == 2) { arow = row & ~15; }
                    v = A[(size_t)arow * HD + kk];
                    if (A2) v += A2[(size_t)row * HD + kk];
                }
                As[rr * ASTR + kk] = v;
            }
            __syncthreads();
            int row = row0 + r;
            float4 acc = b4;
            const float* as = &As[r * ASTR];
            #pragma unroll 8
            for (int k = 0; k < HD; ++k) {
                float a = as[k];
                float4 w = *(const float4*)&Wt[k * 64 + 4 * c];
                acc.x += a * w.x; acc.y += a * w.y;
                acc.z += a * w.z; acc.w += a * w.w;
            }
            if (row < M) {
                acc.x = acc.x * s4.x + sh4.x; acc.y = acc.y * s4.y + sh4.y;
                acc.z = acc.z * s4.z + sh4.z; acc.w = acc.w * s4.w + sh4.w;
                if (relu_flag) {
                    acc.x = fmaxf(acc.x, 0.f); acc.y = fmaxf(acc.y, 0.f);
                    acc.z = fmaxf(acc.z, 0.f); acc.w = fmaxf(acc.w, 0.f);
                }
                if (vf) {
                    float m = vf[row];
                    acc.x *= m; acc.y *= m; acc.z *= m; acc.w *= m;
                }
                float4* cp = (float4*)&C[(size_t)row * HD + half * 64 + 4 * c];
                if (acc_flag) {
                    float4 o = *cp;
                    acc.x += o.x; acc.y += o.y; acc.z += o.z; acc.w += o.w;
                }
                *cp = acc;
            }
        }
    }
}

// ---------------- launcher ----------------

extern "C" void kernel_launch(void* const* d_in, const int* in_sizes, int n_in,
                              void* d_out, int out_size, void* d_ws, size_t ws_size,
                              hipStream_t stream) {
    (void)n_in; (void)ws_size;
    const float* atom_table = (const float*)d_in[0];
    const float* bond_table = (const float*)d_in[1];
    const float* role_table = (const float*)d_in[2];
    const float* lW1 = (const float*)d_in[3];
    const float* lb1 = (const float*)d_in[4];
    const float* lW2 = (const float*)d_in[5];
    const float* lb2 = (const float*)d_in[6];
    const float* gW1 = (const float*)d_in[7];
    const float* gb1 = (const float*)d_in[8];
    const float* gW2 = (const float*)d_in[9];
    const float* gb2 = (const float*)d_in[10];
    const float* lbn_g = (const float*)d_in[11];
    const float* lbn_b = (const float*)d_in[12];
    const float* gbn_g = (const float*)d_in[13];
    const float* gbn_b = (const float*)d_in[14];
    const float* skipW = (const float*)d_in[15];
    const float* skipb = (const float*)d_in[16];
    const float* vvW = (const float*)d_in[17];
    const float* vvb = (const float*)d_in[18];
    const float* kkW = (const float*)d_in[19];
    const float* kkb = (const float*)d_in[20];
    const int* atom_ids = (const int*)d_in[21];
    const int* bond_ids_intra = (const int*)d_in[22];
    const int* bond_ids_global = (const int*)d_in[23];
    const int* intra_ei = (const int*)d_in[24];
    const int* node_ids = (const int*)d_in[25];
    const int* edge_index = (const int*)d_in[26];
    const int* batch = (const int*)d_in[28];

    const int SK = in_sizes[21];          // 128000
    const int EI = in_sizes[22];          // 512000
    const int EG = in_sizes[23];          // 960000
    const int N  = in_sizes[28];          // 60000
    const int L  = in_sizes[4] / HD;      // 3
    const int S  = SK / 16;               // 8000

    // workspace layout (floats)
    float* ws = (float*)d_ws;
    float* h    = ws;                          // SK*HD
    float* t1   = h + (size_t)SK * HD;         // SK*HD  (accumulator / agg)
    float* acc  = t1 + (size_t)SK * HD;        // SK*HD  (temp, also N-row temp)
    float* xsum = acc + (size_t)SK * HD;       // N*HD
    float* n1   = xsum + (size_t)N * HD;       // N*HD
    float* cnt_node = n1 + (size_t)N * HD;     // N
    float* cnt_root = cnt_node + N;            // N
    float* vf = cnt_root + N;                  // SK

    const int B = 256;
    const int gSKrow = (SK + B - 1) / B;
    const int gSK = ((size_t)SK * 32 + B - 1) / B;
    const int gN  = ((size_t)N * 32 + B - 1) / B;
    const int gEI = ((size_t)EI * 32 + B - 1) / B;
    const int gEG = ((size_t)EG * 32 + B - 1) / B;
    const int gS  = ((size_t)S * 32 + B - 1) / B;
    const size_t SKH4 = (size_t)SK * HD * sizeof(float);
    const size_t NH4  = (size_t)N * HD * sizeof(float);

    auto gemm = [&](const float* A, const float* A2, const int* gidx, int gmode,
                    const float* Wp, const float* bp, const float* sc, const float* sh,
                    const float* vfp, float* Cp, int M, int relu, int accf) {
        int ntiles = (M + TS - 1) / TS;
        int grid = ntiles < 2048 ? ntiles : 2048;
        k_gemm128<<<grid, 256, 0, stream>>>(A, A2, gidx, gmode, Wp, bp, sc, sh,
                                            vfp, Cp, M, relu, accf);
    };

    // ---- init ----
    hipMemsetAsync(cnt_node, 0, (size_t)N * sizeof(float), stream);
    hipMemsetAsync(cnt_root, 0, (size_t)N * sizeof(float), stream);
    k_counts<<<gSKrow, B, 0, stream>>>(node_ids, cnt_node, cnt_root, vf, SK);
    k_init_h<<<gSK, B, 0, stream>>>(atom_table, role_table, atom_ids, vf, h, SK);

    for (int l = 0; l < L; ++l) {
        const float* lW1l = lW1 + (size_t)l * HD * HD;
        const float* lb1l = lb1 + (size_t)l * HD;
        const float* lW2l = lW2 + (size_t)l * HD * HD;
        const float* lb2l = lb2 + (size_t)l * HD;
        const float* gW1l = gW1 + (size_t)l * HD * HD;
        const float* gb1l = gb1 + (size_t)l * HD;
        const float* gW2l = gW2 + (size_t)l * HD * HD;
        const float* gb2l = gb2 + (size_t)l * HD;

        // 1) intra-GINE aggregation: t1 = sum_e relu(h[src]+ea)
        hipMemsetAsync(t1, 0, SKH4, stream);
        k_scatter_edges<<<gEI, B, 0, stream>>>(h, intra_ei, intra_ei + EI,
                                               bond_ids_intra, bond_table, t1, EI);
        // 2) hmid = relu((h + t1) @ lW1^T + lb1) -> acc
        gemm(h, t1, nullptr, 0, lW1l, lb1l, nullptr, nullptr, nullptr, acc, SK, 1, 0);
        // 3) h1 = ((acc @ lW2^T + lb2)*lbn_g + lbn_b)*vf -> t1   (store)
        gemm(acc, nullptr, nullptr, 0, lW2l, lb2l, lbn_g + (size_t)l * HD,
             lbn_b + (size_t)l * HD, vf, t1, SK, 0, 0);
        // 4) t1 += h_skip = (h @ skipW^T + skipb)*vf
        gemm(h, nullptr, nullptr, 0, skipW + (size_t)l * HD * HD,
             skipb + (size_t)l * HD, nullptr, nullptr, vf, t1, SK, 0, 1);
        // 5) x_sum = seg_mean(h, safe, N) -> xsum
        hipMemsetAsync(xsum, 0, NH4, stream);
        k_scatter_rows<<<gSK, B, 0, stream>>>(h, node_ids, xsum, SK, 1);
        k_divide<<<gN, B, 0, stream>>>(xsum, cnt_node, N);
        // 6) global-GINE aggregation: n1 = sum_e relu(xsum[src]+ge)
        hipMemsetAsync(n1, 0, NH4, stream);
        k_scatter_edges<<<gEG, B, 0, stream>>>(xsum, edge_index, edge_index + EG,
                                               bond_ids_global, bond_table, n1, EG);
        // 7) hmidN = relu((xsum + n1) @ gW1^T + gb1) -> acc (first N rows)
        gemm(xsum, n1, nullptr, 0, gW1l, gb1l, nullptr, nullptr, nullptr, acc, N, 1, 0);
        // 8) h2n = (acc @ gW2^T + gb2)*gbn_g + gbn_b -> xsum
        gemm(acc, nullptr, nullptr, 0, gW2l, gb2l, gbn_g + (size_t)l * HD,
             gbn_b + (size_t)l * HD, nullptr, xsum, N, 0, 0);
        // 9) t1[i] += xsum[clamped[i]] * vf[i]
        k_gather_add<<<gSK, B, 0, stream>>>(t1, xsum, node_ids, vf, SK);
        // 10) x_vv_c = seg_mean(h[roots], root_safe, N) -> xsum
        hipMemsetAsync(xsum, 0, NH4, stream);
        k_scatter_rows<<<gS, B, 0, stream>>>(h, node_ids, xsum, S, 16);
        k_divide<<<gN, B, 0, stream>>>(xsum, cnt_root, N);
        // 11) t1 += (xsum[clamped] @ vvW^T + vvb)*vf
        gemm(xsum, nullptr, node_ids, 1, vvW + (size_t)l * HD * HD,
             vvb + (size_t)l * HD, nullptr, nullptr, vf, t1, SK, 0, 1);
        // 12) t1 += (h[row & ~15] @ kkW^T + kkb)*vf
        gemm(h, nullptr, nullptr, 2, kkW + (size_t)l * HD * HD,
             kkb + (size_t)l * HD, nullptr, nullptr, vf, t1, SK, 0, 1);
        // 13) h = relu(t1)*vf
        k_relu_mask<<<gSK, B, 0, stream>>>(h, t1, vf, SK);
    }

    // final: node_embs = seg_mean(h, safe, N); out = segment_sum(node_embs, batch, G)
    hipMemsetAsync(xsum, 0, NH4, stream);
    k_scatter_rows<<<gSK, B, 0, stream>>>(h, node_ids, xsum, SK, 1);
    k_divide<<<gN, B, 0, stream>>>(xsum, cnt_node, N);
    hipMemsetAsync(d_out, 0, (size_t)out_size * sizeof(float), stream);
    k_pool<<<gN, B, 0, stream>>>(xsum, batch, (float*)d_out, N);
}

// Round 3
// 2720.948 us; speedup vs baseline: 4.5764x; 4.5764x over previous
//
#include <hip/hip_runtime.h>

#define HD 128      // hidden dim
#define HV2 64      // float2 per row
#define KC 32       // GEMM K-chunk
#define ASTR 132    // padded LDS stride (floats)

// ================= CSR build =================

__global__ __launch_bounds__(256) void k_hist(const int* __restrict__ ids,
        int* __restrict__ deg, int M, int stride) {
    int i = blockIdx.x * blockDim.x + threadIdx.x;
    if (i >= M) return;
    int id = ids[(size_t)i * stride];
    if (id >= 0) atomicAdd(&deg[id], 1);
}

// 4 independent exclusive scans (one per block), start[n] = total
__global__ __launch_bounds__(1024) void k_scan4(
        const int* d0, int* s0, int n0, const int* d1, int* s1, int n1,
        const int* d2, int* s2, int n2, const int* d3, int* s3, int n3) {
    const int* d; int* s; int n;
    if (blockIdx.x == 0)      { d = d0; s = s0; n = n0; }
    else if (blockIdx.x == 1) { d = d1; s = s1; n = n1; }
    else if (blockIdx.x == 2) { d = d2; s = s2; n = n2; }
    else                      { d = d3; s = s3; n = n3; }
    __shared__ int wsum[16];
    int t = threadIdx.x, lane = t & 63, w = t >> 6;
    int carry = 0;
    for (int base = 0; base < n; base += 1024) {
        int i = base + t;
        int v = (i < n) ? d[i] : 0;
        int x = v;
        #pragma unroll
        for (int off = 1; off < 64; off <<= 1) {
            int y = __shfl_up(x, off);
            if (lane >= off) x += y;
        }
        if (lane == 63) wsum[w] = x;
        __syncthreads();
        int wo = 0, tot = 0;
        #pragma unroll
        for (int ww = 0; ww < 16; ++ww) {
            int sv = wsum[ww];
            if (ww < w) wo += sv;
            tot += sv;
        }
        if (i < n) s[i] = carry + wo + (x - v);
        carry += tot;
        __syncthreads();
    }
    if (t == 0) s[n] = carry;
}

__global__ __launch_bounds__(256) void k_fill(const int* __restrict__ ids,
        const int* __restrict__ start, int* __restrict__ cursor,
        int* __restrict__ slots, int M, int stride, int store_row) {
    int i = blockIdx.x * blockDim.x + threadIdx.x;
    if (i >= M) return;
    int id = ids[(size_t)i * stride];
    if (id < 0) return;
    int pos = start[id] + atomicAdd(&cursor[id], 1);
    slots[pos] = store_row ? i * stride : i;
}

// ================= gather-side aggregation (no atomics) =================

// one wave per row: out[w] = sum_p relu(X[src[slots[p]]] + btab[bid[slots[p]]])
__global__ __launch_bounds__(256) void k_gine_csr(const float* __restrict__ X,
        const int* __restrict__ srcs, const int* __restrict__ bids,
        const float* __restrict__ btab, const int* __restrict__ start,
        const int* __restrict__ slots, float* __restrict__ out, int Nrows) {
    int w = (blockIdx.x * 256 + threadIdx.x) >> 6;
    int lane = threadIdx.x & 63;
    if (w >= Nrows) return;
    int s0 = start[w], s1 = start[w + 1];
    float2 acc = make_float2(0.f, 0.f);
    for (int p = s0; p < s1; ++p) {
        int e = slots[p];
        int s = srcs[e], b = bids[e];
        float2 x = ((const float2*)X)[(size_t)s * HV2 + lane];
        float2 bb = ((const float2*)btab)[(size_t)b * HV2 + lane];
        acc.x += fmaxf(x.x + bb.x, 0.f);
        acc.y += fmaxf(x.y + bb.y, 0.f);
    }
    ((float2*)out)[(size_t)w * HV2 + lane] = acc;
}

// one wave per node: out[w] = mean of X rows listed in slots
__global__ __launch_bounds__(256) void k_segmean_csr(const float* __restrict__ X,
        const int* __restrict__ start, const int* __restrict__ slots,
        float* __restrict__ out, int Nrows) {
    int w = (blockIdx.x * 256 + threadIdx.x) >> 6;
    int lane = threadIdx.x & 63;
    if (w >= Nrows) return;
    int s0 = start[w], s1 = start[w + 1];
    float inv = 1.0f / fmaxf((float)(s1 - s0), 1.0f);
    float2 acc = make_float2(0.f, 0.f);
    for (int p = s0; p < s1; ++p) {
        int r = slots[p];
        float2 x = ((const float2*)X)[(size_t)r * HV2 + lane];
        acc.x += x.x; acc.y += x.y;
    }
    acc.x *= inv; acc.y *= inv;
    ((float2*)out)[(size_t)w * HV2 + lane] = acc;
}

// ================= elementwise =================

__global__ __launch_bounds__(256) void k_vf(const int* __restrict__ node_ids,
        float* __restrict__ vf, int SK) {
    int i = blockIdx.x * blockDim.x + threadIdx.x;
    if (i < SK) vf[i] = (node_ids[i] >= 0) ? 1.0f : 0.0f;
}

__global__ __launch_bounds__(256) void k_init_h(const float* __restrict__ at,
        const float* __restrict__ rt, const int* __restrict__ atom_ids,
        const float* __restrict__ vf, float* __restrict__ h, int SK) {
    int t = blockIdx.x * blockDim.x + threadIdx.x;
    int i = t >> 6, c = t & 63;
    if (i >= SK) return;
    float2 a = ((const float2*)at)[(size_t)atom_ids[i] * HV2 + c];
    int role = ((i & 15) == 0) ? 1 : 0;
    float2 r = ((const float2*)rt)[role * HV2 + c];
    float m = vf[i];
    float2 v;
    v.x = (a.x + r.x) * m; v.y = (a.y + r.y) * m;
    ((float2*)h)[(size_t)i * HV2 + c] = v;
}

// acc[i] += src[max(idx[i],0)] * vf[i]
__global__ __launch_bounds__(256) void k_gather_add(float* __restrict__ acc,
        const float* __restrict__ src, const int* __restrict__ idx,
        const float* __restrict__ vf, int M) {
    int t = blockIdx.x * blockDim.x + threadIdx.x;
    int i = t >> 6, c = t & 63;
    if (i >= M) return;
    int id = idx[i]; id = (id > 0) ? id : 0;
    float m = vf[i];
    float2 s = ((const float2*)src)[(size_t)id * HV2 + c];
    float2* a = &((float2*)acc)[(size_t)i * HV2 + c];
    float2 v = *a;
    v.x += s.x * m; v.y += s.y * m;
    *a = v;
}

__global__ __launch_bounds__(256) void k_relu_mask(float* __restrict__ h,
        const float* __restrict__ tin, const float* __restrict__ vf, int M) {
    int t = blockIdx.x * blockDim.x + threadIdx.x;
    int i = t >> 6, c = t & 63;
    if (i >= M) return;
    float m = vf[i];
    float2 v = ((const float2*)tin)[(size_t)i * HV2 + c];
    v.x = fmaxf(v.x, 0.f) * m; v.y = fmaxf(v.y, 0.f) * m;
    ((float2*)h)[(size_t)i * HV2 + c] = v;
}

__global__ __launch_bounds__(256) void k_pool(const float* __restrict__ xsum,
        const int* __restrict__ batch, float* __restrict__ out, int N) {
    int t = blockIdx.x * blockDim.x + threadIdx.x;
    int n = t >> 6, c = t & 63;
    if (n >= N) return;
    int g = batch[n];
    float2 x = ((const float2*)xsum)[(size_t)n * HV2 + c];
    float* o = out + (size_t)g * HD + c * 2;
    atomicAdd(o + 0, x.x);
    atomicAdd(o + 1, x.y);
}

// ================= GEMM: C[M,128] = epi((A[gather]+A2) @ W^T + b) =================
// 128x128 tile / 256 threads / 8x8 register blocking. gmode: 0 id, 1 max(gidx,0), 2 row&~15.
// In-place (C==A) is safe for gmode 0: each block reads only the rows it writes,
// and all reads precede the epilogue write.
__global__ __launch_bounds__(256) void k_gemm_v2(
        const float* __restrict__ A, const float* __restrict__ A2,
        const int* __restrict__ gidx, int gmode,
        const float* __restrict__ W, const float* __restrict__ bias,
        const float* __restrict__ scale, const float* __restrict__ shift,
        const float* __restrict__ vf, float* __restrict__ C,
        int M, int relu_flag, int acc_flag) {
    __shared__ float As[KC][ASTR];
    __shared__ float Ws[KC][ASTR];
    const int t = threadIdx.x;
    const int tx = t & 15, ty = t >> 4;
    const int row0 = blockIdx.x * 128;
    const int sr = t >> 1;
    const int sh = (t & 1) * 16;

    float acc[8][8];
    #pragma unroll
    for (int i = 0; i < 8; ++i)
        #pragma unroll
        for (int j = 0; j < 8; ++j) acc[i][j] = 0.f;

    int arow = row0 + sr;
    bool aval = arow < M;
    int asrc = arow;
    if (aval) {
        if (gmode == 1) { int g = gidx[arow]; asrc = (g > 0) ? g : 0; }
        else if (gmode == 2) { asrc = arow & ~15; }
    } else asrc = 0;
    const float4* Arow4 = (const float4*)(A + (size_t)asrc * HD);
    const float4* A2row4 = A2 ? (const float4*)(A2 + (size_t)arow * HD) : (const float4*)nullptr;
    const float4* Wrow4 = (const float4*)(W + (size_t)sr * HD);

    for (int kc = 0; kc < HD; kc += KC) {
        __syncthreads();
        #pragma unroll
        for (int j = 0; j < 4; ++j) {
            int kk = sh + 4 * j;
            int k = kc + kk;
            float4 v = make_float4(0.f, 0.f, 0.f, 0.f);
            if (aval) {
                v = Arow4[k >> 2];
                if (A2) {
                    float4 u = A2row4[k >> 2];
                    v.x += u.x; v.y += u.y; v.z += u.z; v.w += u.w;
                }
            }
            As[kk + 0][sr] = v.x; As[kk + 1][sr] = v.y;
            As[kk + 2][sr] = v.z; As[kk + 3][sr] = v.w;
            float4 wv = Wrow4[k >> 2];
            Ws[kk + 0][sr] = wv.x; Ws[kk + 1][sr] = wv.y;
            Ws[kk + 2][sr] = wv.z; Ws[kk + 3][sr] = wv.w;
        }
        __syncthreads();
        #pragma unroll
        for (int kk = 0; kk < KC; ++kk) {
            float4 a0 = *(const float4*)&As[kk][ty * 8];
            float4 a1 = *(const float4*)&As[kk][ty * 8 + 4];
            float4 w0 = *(const float4*)&Ws[kk][tx * 8];
            float4 w1 = *(const float4*)&Ws[kk][tx * 8 + 4];
            float av[8] = {a0.x, a0.y, a0.z, a0.w, a1.x, a1.y, a1.z, a1.w};
            float wv[8] = {w0.x, w0.y, w0.z, w0.w, w1.x, w1.y, w1.z, w1.w};
            #pragma unroll
            for (int i = 0; i < 8; ++i)
                #pragma unroll
                for (int j = 0; j < 8; ++j)
                    acc[i][j] = fmaf(av[i], wv[j], acc[i][j]);
        }
    }

    float4 b0 = ((const float4*)bias)[tx * 2];
    float4 b1 = ((const float4*)bias)[tx * 2 + 1];
    float4 s0 = make_float4(1.f, 1.f, 1.f, 1.f), s1 = s0;
    float4 h0 = make_float4(0.f, 0.f, 0.f, 0.f), h1 = h0;
    if (scale) {
        s0 = ((const float4*)scale)[tx * 2]; s1 = ((const float4*)scale)[tx * 2 + 1];
        h0 = ((const float4*)shift)[tx * 2]; h1 = ((const float4*)shift)[tx * 2 + 1];
    }
    #pragma unroll
    for (int i = 0; i < 8; ++i) {
        int row = row0 + ty * 8 + i;
        if (row >= M) break;
        float m = vf ? vf[row] : 1.0f;
        float o[8];
        o[0] = acc[i][0] + b0.x; o[1] = acc[i][1] + b0.y;
        o[2] = acc[i][2] + b0.z; o[3] = acc[i][3] + b0.w;
        o[4] = acc[i][4] + b1.x; o[5] = acc[i][5] + b1.y;
        o[6] = acc[i][6] + b1.z; o[7] = acc[i][7] + b1.w;
        if (scale) {
            o[0] = o[0] * s0.x + h0.x; o[1] = o[1] * s0.y + h0.y;
            o[2] = o[2] * s0.z + h0.z; o[3] = o[3] * s0.w + h0.w;
            o[4] = o[4] * s1.x + h1.x; o[5] = o[5] * s1.y + h1.y;
            o[6] = o[6] * s1.z + h1.z; o[7] = o[7] * s1.w + h1.w;
        }
        if (relu_flag) {
            #pragma unroll
            for (int j = 0; j < 8; ++j) o[j] = fmaxf(o[j], 0.f);
        }
        #pragma unroll
        for (int j = 0; j < 8; ++j) o[j] *= m;
        float4* cp = (float4*)(C + (size_t)row * HD + tx * 8);
        if (acc_flag) {
            float4 c0 = cp[0], c1 = cp[1];
            o[0] += c0.x; o[1] += c0.y; o[2] += c0.z; o[3] += c0.w;
            o[4] += c1.x; o[5] += c1.y; o[6] += c1.z; o[7] += c1.w;
        }
        cp[0] = make_float4(o[0], o[1], o[2], o[3]);
        cp[1] = make_float4(o[4], o[5], o[6], o[7]);
    }
}

// ================= launcher =================

extern "C" void kernel_launch(void* const* d_in, const int* in_sizes, int n_in,
                              void* d_out, int out_size, void* d_ws, size_t ws_size,
                              hipStream_t stream) {
    (void)n_in; (void)ws_size;
    const float* atom_table = (const float*)d_in[0];
    const float* bond_table = (const float*)d_in[1];
    const float* role_table = (const float*)d_in[2];
    const float* lW1 = (const float*)d_in[3];
    const float* lb1 = (const float*)d_in[4];
    const float* lW2 = (const float*)d_in[5];
    const float* lb2 = (const float*)d_in[6];
    const float* gW1 = (const float*)d_in[7];
    const float* gb1 = (const float*)d_in[8];
    const float* gW2 = (const float*)d_in[9];
    const float* gb2 = (const float*)d_in[10];
    const float* lbn_g = (const float*)d_in[11];
    const float* lbn_b = (const float*)d_in[12];
    const float* gbn_g = (const float*)d_in[13];
    const float* gbn_b = (const float*)d_in[14];
    const float* skipW = (const float*)d_in[15];
    const float* skipb = (const float*)d_in[16];
    const float* vvW = (const float*)d_in[17];
    const float* vvb = (const float*)d_in[18];
    const float* kkW = (const float*)d_in[19];
    const float* kkb = (const float*)d_in[20];
    const int* atom_ids = (const int*)d_in[21];
    const int* bond_ids_intra = (const int*)d_in[22];
    const int* bond_ids_global = (const int*)d_in[23];
    const int* intra_ei = (const int*)d_in[24];
    const int* node_ids = (const int*)d_in[25];
    const int* edge_index = (const int*)d_in[26];
    const int* batch = (const int*)d_in[28];

    const int SK = in_sizes[21];
    const int EI = in_sizes[22];
    const int EG = in_sizes[23];
    const int N  = in_sizes[28];
    const int L  = in_sizes[4] / HD;
    const int S  = SK / 16;

    // ---- workspace layout (~206 MB total; must stay < ~258 MB proven capacity) ----
    float* f = (float*)d_ws;
    float* h    = f;                         // SK*HD
    float* t1   = h   + (size_t)SK * HD;     // SK*HD
    float* acc  = t1  + (size_t)SK * HD;     // SK*HD; acc[0:N)=means/z/h2, acc[N:2N)=agg/rootmean
    float* vf   = acc + (size_t)SK * HD;     // SK
    int* ip = (int*)(vf + SK);
    int* degI   = ip;              // SK (deg, then cursor)
    int* degG   = degI + SK;       // N
    int* degN   = degG + N;        // N
    int* degR   = degN + N;        // N
    int* startI = degR + N;        // SK+1
    int* startG = startI + SK + 1; // N+1
    int* startN = startG + N + 1;  // N+1
    int* startR = startN + N + 1;  // N+1
    int* slotI  = startR + N + 1;  // EI
    int* slotG  = slotI + EI;      // EG
    int* slotN  = slotG + EG;      // SK
    int* slotR  = slotN + SK;      // S

    float* nmean = acc;                       // N rows (means / z / h2 in place)
    float* nbuf2 = acc + (size_t)N * HD;      // N rows (agg / root means)

    const int B = 256;
    const int gSKe = (int)(((size_t)SK * 64 + B - 1) / B);
    const int gwSK = (SK * 64 + B - 1) / B;
    const int gwN  = (N * 64 + B - 1) / B;
    const int gNe  = (int)(((size_t)N * 64 + B - 1) / B);

    auto gemm = [&](const float* A, const float* A2, const int* gidx, int gmode,
                    const float* Wp, const float* bp, const float* sc, const float* sh,
                    const float* vfp, float* Cp, int M, int relu, int accf) {
        int grid = (M + 127) / 128;
        k_gemm_v2<<<grid, 256, 0, stream>>>(A, A2, gidx, gmode, Wp, bp, sc, sh,
                                            vfp, Cp, M, relu, accf);
    };

    const int* intra_dst = intra_ei + EI;
    const int* glob_dst  = edge_index + EG;

    // ---- CSR build (reused by all layers) ----
    hipMemsetAsync(degI, 0, (size_t)(SK + 3 * N) * sizeof(int), stream);
    k_hist<<<(EI + B - 1) / B, B, 0, stream>>>(intra_dst, degI, EI, 1);
    k_hist<<<(EG + B - 1) / B, B, 0, stream>>>(glob_dst, degG, EG, 1);
    k_hist<<<(SK + B - 1) / B, B, 0, stream>>>(node_ids, degN, SK, 1);
    k_hist<<<(S + B - 1) / B, B, 0, stream>>>(node_ids, degR, S, 16);
    k_scan4<<<4, 1024, 0, stream>>>(degI, startI, SK, degG, startG, N,
                                    degN, startN, N, degR, startR, N);
    hipMemsetAsync(degI, 0, (size_t)(SK + 3 * N) * sizeof(int), stream);
    k_fill<<<(EI + B - 1) / B, B, 0, stream>>>(intra_dst, startI, degI, slotI, EI, 1, 0);
    k_fill<<<(EG + B - 1) / B, B, 0, stream>>>(glob_dst, startG, degG, slotG, EG, 1, 0);
    k_fill<<<(SK + B - 1) / B, B, 0, stream>>>(node_ids, startN, degN, slotN, SK, 1, 0);
    k_fill<<<(S + B - 1) / B, B, 0, stream>>>(node_ids, startR, degR, slotR, S, 16, 1);

    // ---- init ----
    k_vf<<<(SK + B - 1) / B, B, 0, stream>>>(node_ids, vf, SK);
    k_init_h<<<gSKe, B, 0, stream>>>(atom_table, role_table, atom_ids, vf, h, SK);

    for (int l = 0; l < L; ++l) {
        const size_t lo = (size_t)l * HD * HD;
        const size_t lb = (size_t)l * HD;
        // 1) t1 = intra-GINE agg (CSR gather)
        k_gine_csr<<<gwSK, B, 0, stream>>>(h, intra_ei, bond_ids_intra, bond_table,
                                           startI, slotI, t1, SK);
        // 2) acc = relu((h+t1) @ lW1^T + lb1)
        gemm(h, t1, nullptr, 0, lW1 + lo, lb1 + lb, nullptr, nullptr, nullptr, acc, SK, 1, 0);
        // 3) t1 = ((acc @ lW2^T + lb2)*lbn_g + lbn_b)*vf        [acc now dead]
        gemm(acc, nullptr, nullptr, 0, lW2 + lo, lb2 + lb, lbn_g + lb, lbn_b + lb,
             vf, t1, SK, 0, 0);
        // 4) t1 += (h @ skipW^T + skipb)*vf
        gemm(h, nullptr, nullptr, 0, skipW + lo, skipb + lb, nullptr, nullptr,
             vf, t1, SK, 0, 1);
        // 5) nmean = seg_mean(h, node CSR)
        k_segmean_csr<<<gwN, B, 0, stream>>>(h, startN, slotN, nmean, N);
        // 6) nbuf2 = global-GINE agg (gather from nmean; disjoint rows)
        k_gine_csr<<<gwN, B, 0, stream>>>(nmean, edge_index, bond_ids_global, bond_table,
                                          startG, slotG, nbuf2, N);
        // 7) nmean = relu((nmean+nbuf2) @ gW1^T + gb1)           [in-place safe]
        gemm(nmean, nbuf2, nullptr, 0, gW1 + lo, gb1 + lb, nullptr, nullptr, nullptr,
             nmean, N, 1, 0);
        // 8) nmean = (nmean @ gW2^T + gb2)*gbn_g + gbn_b          [in-place safe]
        gemm(nmean, nullptr, nullptr, 0, gW2 + lo, gb2 + lb, gbn_g + lb, gbn_b + lb,
             nullptr, nmean, N, 0, 0);
        // 9) t1 += nmean[clamped]*vf
        k_gather_add<<<gSKe, B, 0, stream>>>(t1, nmean, node_ids, vf, SK);
        // 10) nbuf2 = root seg_mean(h, root CSR)
        k_segmean_csr<<<gwN, B, 0, stream>>>(h, startR, slotR, nbuf2, N);
        // 11) t1 += (nbuf2[clamped] @ vvW^T + vvb)*vf
        gemm(nbuf2, nullptr, node_ids, 1, vvW + lo, vvb + lb, nullptr, nullptr,
             vf, t1, SK, 0, 1);
        // 12) t1 += (h[row&~15] @ kkW^T + kkb)*vf
        gemm(h, nullptr, nullptr, 2, kkW + lo, kkb + lb, nullptr, nullptr,
             vf, t1, SK, 0, 1);
        // 13) h = relu(t1)*vf
        k_relu_mask<<<gSKe, B, 0, stream>>>(h, t1, vf, SK);
    }

    // final: node_embs = seg_mean(h); out = segment_sum(node_embs, batch)
    k_segmean_csr<<<gwN, B, 0, stream>>>(h, startN, slotN, nmean, N);
    hipMemsetAsync(d_out, 0, (size_t)out_size * sizeof(float), stream);
    k_pool<<<gNe, B, 0, stream>>>(nmean, batch, (float*)d_out, N);
}

// Round 4
// 1984.956 us; speedup vs baseline: 6.2732x; 1.3708x over previous
//
#include <hip/hip_runtime.h>

typedef unsigned short ushort_t;
typedef unsigned int uint_t;
typedef __attribute__((ext_vector_type(8))) short v8s;   // 8 bf16 (4 VGPRs) MFMA A/B frag
typedef __attribute__((ext_vector_type(4))) float v4f;   // MFMA C/D frag

#define HD 128
#define MFMA16(a, b, c) __builtin_amdgcn_mfma_f32_16x16x32_bf16((a), (b), (c), 0, 0, 0)

__device__ __forceinline__ float b2f(ushort_t u) {
    union { uint_t i; float f; } v; v.i = ((uint_t)u) << 16; return v.f;
}
__device__ __forceinline__ ushort_t f2b(float f) {
    union { float f; uint_t i; } v; v.f = f;
    uint_t u = v.i;
    return (ushort_t)((u + 0x7FFFu + ((u >> 16) & 1u)) >> 16);
}

// ================= CSR build (unchanged from R3) =================

__global__ __launch_bounds__(256) void k_hist(const int* __restrict__ ids,
        int* __restrict__ deg, int M, int stride) {
    int i = blockIdx.x * blockDim.x + threadIdx.x;
    if (i >= M) return;
    int id = ids[(size_t)i * stride];
    if (id >= 0) atomicAdd(&deg[id], 1);
}

__global__ __launch_bounds__(1024) void k_scan4(
        const int* d0, int* s0, int n0, const int* d1, int* s1, int n1,
        const int* d2, int* s2, int n2, const int* d3, int* s3, int n3) {
    const int* d; int* s; int n;
    if (blockIdx.x == 0)      { d = d0; s = s0; n = n0; }
    else if (blockIdx.x == 1) { d = d1; s = s1; n = n1; }
    else if (blockIdx.x == 2) { d = d2; s = s2; n = n2; }
    else                      { d = d3; s = s3; n = n3; }
    __shared__ int wsum[16];
    int t = threadIdx.x, lane = t & 63, w = t >> 6;
    int carry = 0;
    for (int base = 0; base < n; base += 1024) {
        int i = base + t;
        int v = (i < n) ? d[i] : 0;
        int x = v;
        #pragma unroll
        for (int off = 1; off < 64; off <<= 1) {
            int y = __shfl_up(x, off);
            if (lane >= off) x += y;
        }
        if (lane == 63) wsum[w] = x;
        __syncthreads();
        int wo = 0, tot = 0;
        #pragma unroll
        for (int ww = 0; ww < 16; ++ww) {
            int sv = wsum[ww];
            if (ww < w) wo += sv;
            tot += sv;
        }
        if (i < n) s[i] = carry + wo + (x - v);
        carry += tot;
        __syncthreads();
    }
    if (t == 0) s[n] = carry;
}

__global__ __launch_bounds__(256) void k_fill(const int* __restrict__ ids,
        const int* __restrict__ start, int* __restrict__ cursor,
        int* __restrict__ slots, int M, int stride, int store_row) {
    int i = blockIdx.x * blockDim.x + threadIdx.x;
    if (i >= M) return;
    int id = ids[(size_t)i * stride];
    if (id < 0) return;
    int pos = start[id] + atomicAdd(&cursor[id], 1);
    slots[pos] = store_row ? i * stride : i;
}

// ================= weight/bias prep =================

// wbuf[(fam*L+l)*16384 + n*128 + k] = bf16( src_fam[l][n][k] * scale_fam[n] )
// fam: 0 lW1, 1 lW2*lbn_g, 2 gW1, 3 gW2*gbn_g, 4 skipW, 5 vvW, 6 kkW
__global__ __launch_bounds__(256) void k_convert_w(
        const float* lW1, const float* lW2, const float* gW1, const float* gW2,
        const float* skipW, const float* vvW, const float* kkW,
        const float* lbn_g, const float* gbn_g,
        ushort_t* __restrict__ wbuf, int L) {
    int idx = blockIdx.x * blockDim.x + threadIdx.x;
    int total = 7 * L * 16384;
    if (idx >= total) return;
    int fam = idx / (L * 16384);
    int r = idx % (L * 16384);
    int l = r / 16384, e = r % 16384, n = e / 128;
    const float* src;
    float sc = 1.0f;
    switch (fam) {
        case 0: src = lW1; break;
        case 1: src = lW2; sc = lbn_g[l * 128 + n]; break;
        case 2: src = gW1; break;
        case 3: src = gW2; sc = gbn_g[l * 128 + n]; break;
        case 4: src = skipW; break;
        case 5: src = vvW; break;
        default: src = kkW; break;
    }
    wbuf[idx] = f2b(src[(size_t)l * 16384 + e] * sc);
}

// cb[l*128+n] = lb2*lbn_g + lbn_b + skipb + vvb + kkb ;  b2g = gb2*gbn_g + gbn_b
__global__ __launch_bounds__(256) void k_bias(
        const float* lb2, const float* lbn_g, const float* lbn_b,
        const float* skipb, const float* vvb, const float* kkb,
        const float* gb2, const float* gbn_g, const float* gbn_b,
        float* __restrict__ cb, float* __restrict__ b2g, int total) {
    int i = blockIdx.x * blockDim.x + threadIdx.x;
    if (i >= total) return;
    cb[i] = lb2[i] * lbn_g[i] + lbn_b[i] + skipb[i] + vvb[i] + kkb[i];
    b2g[i] = gb2[i] * gbn_g[i] + gbn_b[i];
}

// ================= elementwise / graph kernels (bf16) =================

__global__ __launch_bounds__(256) void k_vf(const int* __restrict__ node_ids,
        float* __restrict__ vf, int SK) {
    int i = blockIdx.x * blockDim.x + threadIdx.x;
    if (i < SK) vf[i] = (node_ids[i] >= 0) ? 1.0f : 0.0f;
}

__global__ __launch_bounds__(256) void k_init_h(const float* __restrict__ at,
        const float* __restrict__ rt, const int* __restrict__ atom_ids,
        const float* __restrict__ vf, ushort_t* __restrict__ h, int SK) {
    int t = blockIdx.x * blockDim.x + threadIdx.x;
    int i = t >> 6, lane = t & 63;
    if (i >= SK) return;
    float2 a = ((const float2*)(at + (size_t)atom_ids[i] * HD))[lane];
    int role = ((i & 15) == 0) ? 1 : 0;
    float2 r = ((const float2*)(rt + (size_t)role * HD))[lane];
    float m = vf[i];
    uint_t o = (uint_t)f2b((a.x + r.x) * m) | ((uint_t)f2b((a.y + r.y) * m) << 16);
    *(uint_t*)(h + (size_t)i * HD + lane * 2) = o;
}

// outz[w] = X[w] + sum_p relu(X[src[slots[p]]] + btab[bid[slots[p]]])   (bf16)
__global__ __launch_bounds__(256) void k_gine_z(const ushort_t* __restrict__ X,
        const int* __restrict__ srcs, const int* __restrict__ bids,
        const float* __restrict__ btab, const int* __restrict__ start,
        const int* __restrict__ slots, ushort_t* __restrict__ outz, int Nrows) {
    int w = (blockIdx.x * 256 + threadIdx.x) >> 6;
    int lane = threadIdx.x & 63;
    if (w >= Nrows) return;
    int s0 = start[w], s1 = start[w + 1];
    uint_t xb = *(const uint_t*)(X + (size_t)w * HD + lane * 2);
    float ax = b2f((ushort_t)(xb & 0xFFFF)), ay = b2f((ushort_t)(xb >> 16));
    for (int p = s0; p < s1; ++p) {
        int e = slots[p];
        int s = srcs[e], b = bids[e];
        uint_t u = *(const uint_t*)(X + (size_t)s * HD + lane * 2);
        float2 bt = ((const float2*)(btab + (size_t)b * HD))[lane];
        ax += fmaxf(b2f((ushort_t)(u & 0xFFFF)) + bt.x, 0.f);
        ay += fmaxf(b2f((ushort_t)(u >> 16)) + bt.y, 0.f);
    }
    uint_t o = (uint_t)f2b(ax) | ((uint_t)f2b(ay) << 16);
    *(uint_t*)(outz + (size_t)w * HD + lane * 2) = o;
}

// out[w] = mean of X rows listed in slots (bf16 in/out)
__global__ __launch_bounds__(256) void k_segmean(const ushort_t* __restrict__ X,
        const int* __restrict__ start, const int* __restrict__ slots,
        ushort_t* __restrict__ out, int Nrows) {
    int w = (blockIdx.x * 256 + threadIdx.x) >> 6;
    int lane = threadIdx.x & 63;
    if (w >= Nrows) return;
    int s0 = start[w], s1 = start[w + 1];
    float inv = 1.0f / fmaxf((float)(s1 - s0), 1.0f);
    float ax = 0.f, ay = 0.f;
    for (int p = s0; p < s1; ++p) {
        int r = slots[p];
        uint_t u = *(const uint_t*)(X + (size_t)r * HD + lane * 2);
        ax += b2f((ushort_t)(u & 0xFFFF));
        ay += b2f((ushort_t)(u >> 16));
    }
    uint_t o = (uint_t)f2b(ax * inv) | ((uint_t)f2b(ay * inv) << 16);
    *(uint_t*)(out + (size_t)w * HD + lane * 2) = o;
}

__global__ __launch_bounds__(256) void k_pool(const ushort_t* __restrict__ xsum,
        const int* __restrict__ batch, float* __restrict__ out, int N) {
    int t = blockIdx.x * blockDim.x + threadIdx.x;
    int n = t >> 6, lane = t & 63;
    if (n >= N) return;
    int g = batch[n];
    uint_t u = *(const uint_t*)(xsum + (size_t)n * HD + lane * 2);
    float* o = out + (size_t)g * HD + lane * 2;
    atomicAdd(o + 0, b2f((ushort_t)(u & 0xFFFF)));
    atomicAdd(o + 1, b2f((ushort_t)(u >> 16)));
}

// ================= MFMA GEMM: C = maybe_relu(A @ W^T + bias), bf16 =================
// One wave = 16 output rows; A,W row-major bf16 [*,128]; K=128 = 4 frags/lane.
// A-frag layout: row=lane&15, k=(lane>>4)*8+j ; B-frag: W row n=lane&15, same k.
// C/D: col=lane&15, row=(lane>>4)*4+reg. No LDS, no barriers.
__global__ __launch_bounds__(256) void k_mfma1(const ushort_t* __restrict__ A,
        const ushort_t* __restrict__ Wb, const float* __restrict__ bias,
        ushort_t* __restrict__ C, int M, int relu_flag) {
    int lane = threadIdx.x & 63, wave = threadIdx.x >> 6;
    int row0 = (blockIdx.x * 4 + wave) * 16;
    if (row0 >= M) return;
    int m = lane & 15, quad = lane >> 4;
    int ar = row0 + m; if (ar > M - 1) ar = M - 1;
    const v8s* Ar = (const v8s*)(A + (size_t)ar * HD);
    v8s a0 = Ar[quad], a1 = Ar[4 + quad], a2 = Ar[8 + quad], a3 = Ar[12 + quad];
    int rbase = row0 + quad * 4;
    for (int nt = 0; nt < 8; ++nt) {
        const v8s* Wr = (const v8s*)(Wb + (size_t)(nt * 16 + m) * HD);
        v4f acc = {0.f, 0.f, 0.f, 0.f};
        acc = MFMA16(a0, Wr[quad], acc);
        acc = MFMA16(a1, Wr[4 + quad], acc);
        acc = MFMA16(a2, Wr[8 + quad], acc);
        acc = MFMA16(a3, Wr[12 + quad], acc);
        int col = nt * 16 + m;
        float bc = bias[col];
        #pragma unroll
        for (int r = 0; r < 4; ++r) {
            int row = rbase + r;
            if (row < M) {
                float v = acc[r] + bc;
                if (relu_flag) v = fmaxf(v, 0.f);
                C[(size_t)row * HD + col] = f2b(v);
            }
        }
    }
}

// ================= fused tail: h' = relu(hmid@W2g + h@Wsk + rootm[c]@Wvv
//                                        + h[root]@Wkk + h2[c] + cb) * vf =================
// M = SK (multiple of 64). Writes hout (must differ from h).
__global__ __launch_bounds__(256) void k_mfma_fused(
        const ushort_t* __restrict__ hmid, const ushort_t* __restrict__ h,
        const ushort_t* __restrict__ rootm, const ushort_t* __restrict__ h2,
        const int* __restrict__ node_ids, const float* __restrict__ vf,
        const ushort_t* __restrict__ W2g, const ushort_t* __restrict__ Wsk,
        const ushort_t* __restrict__ Wvv, const ushort_t* __restrict__ Wkk,
        const float* __restrict__ cb, ushort_t* __restrict__ hout, int M) {
    int lane = threadIdx.x & 63, wave = threadIdx.x >> 6;
    int row0 = (blockIdx.x * 4 + wave) * 16;
    if (row0 >= M) return;
    int m = lane & 15, quad = lane >> 4;
    int ar = row0 + m;
    int nid = node_ids[ar]; int nc = nid > 0 ? nid : 0;
    const v8s* A0 = (const v8s*)(hmid + (size_t)ar * HD);
    const v8s* A1 = (const v8s*)(h + (size_t)ar * HD);
    const v8s* A2 = (const v8s*)(rootm + (size_t)nc * HD);
    const v8s* A3 = (const v8s*)(h + (size_t)(ar & ~15) * HD);
    v8s f0[4], f1[4], f2[4], f3[4];
    #pragma unroll
    for (int c = 0; c < 4; ++c) {
        f0[c] = A0[c * 4 + quad]; f1[c] = A1[c * 4 + quad];
        f2[c] = A2[c * 4 + quad]; f3[c] = A3[c * 4 + quad];
    }
    int nidr[4]; float vfr[4];
    #pragma unroll
    for (int r = 0; r < 4; ++r) {
        int row = row0 + quad * 4 + r;
        int q = node_ids[row];
        nidr[r] = q > 0 ? q : 0;
        vfr[r] = vf[row];
    }
    for (int nt = 0; nt < 8; ++nt) {
        int wr = nt * 16 + m;
        const v8s* W0 = (const v8s*)(W2g + (size_t)wr * HD);
        const v8s* W1 = (const v8s*)(Wsk + (size_t)wr * HD);
        const v8s* W2 = (const v8s*)(Wvv + (size_t)wr * HD);
        const v8s* W3 = (const v8s*)(Wkk + (size_t)wr * HD);
        v4f acc = {0.f, 0.f, 0.f, 0.f};
        #pragma unroll
        for (int c = 0; c < 4; ++c) {
            acc = MFMA16(f0[c], W0[c * 4 + quad], acc);
            acc = MFMA16(f1[c], W1[c * 4 + quad], acc);
            acc = MFMA16(f2[c], W2[c * 4 + quad], acc);
            acc = MFMA16(f3[c], W3[c * 4 + quad], acc);
        }
        int col = nt * 16 + m;
        float bc = cb[col];
        #pragma unroll
        for (int r = 0; r < 4; ++r) {
            int row = row0 + quad * 4 + r;
            float v = acc[r] + bc + b2f(h2[(size_t)nidr[r] * HD + col]);
            v = fmaxf(v, 0.f) * vfr[r];
            hout[(size_t)row * HD + col] = f2b(v);
        }
    }
}

// ================= launcher =================

extern "C" void kernel_launch(void* const* d_in, const int* in_sizes, int n_in,
                              void* d_out, int out_size, void* d_ws, size_t ws_size,
                              hipStream_t stream) {
    (void)n_in; (void)ws_size;
    const float* atom_table = (const float*)d_in[0];
    const float* bond_table = (const float*)d_in[1];
    const float* role_table = (const float*)d_in[2];
    const float* lW1 = (const float*)d_in[3];
    const float* lb1 = (const float*)d_in[4];
    const float* lW2 = (const float*)d_in[5];
    const float* lb2 = (const float*)d_in[6];
    const float* gW1 = (const float*)d_in[7];
    const float* gb1 = (const float*)d_in[8];
    const float* gW2 = (const float*)d_in[9];
    const float* gb2 = (const float*)d_in[10];
    const float* lbn_g = (const float*)d_in[11];
    const float* lbn_b = (const float*)d_in[12];
    const float* gbn_g = (const float*)d_in[13];
    const float* gbn_b = (const float*)d_in[14];
    const float* skipW = (const float*)d_in[15];
    const float* skipb = (const float*)d_in[16];
    const float* vvW = (const float*)d_in[17];
    const float* vvb = (const float*)d_in[18];
    const float* kkW = (const float*)d_in[19];
    const float* kkb = (const float*)d_in[20];
    const int* atom_ids = (const int*)d_in[21];
    const int* bond_ids_intra = (const int*)d_in[22];
    const int* bond_ids_global = (const int*)d_in[23];
    const int* intra_ei = (const int*)d_in[24];
    const int* node_ids = (const int*)d_in[25];
    const int* edge_index = (const int*)d_in[26];
    const int* batch = (const int*)d_in[28];

    const int SK = in_sizes[21];
    const int EI = in_sizes[22];
    const int EG = in_sizes[23];
    const int N  = in_sizes[28];
    const int L  = in_sizes[4] / HD;
    const int S  = SK / 16;

    // ---- workspace layout (~186 MB) ----
    ushort_t* us = (ushort_t*)d_ws;
    ushort_t* hA    = us;                            // SK*HD bf16
    ushort_t* hB    = hA + (size_t)SK * HD;          // SK*HD (z / next-h, ping-pong)
    ushort_t* hmid  = hB + (size_t)SK * HD;          // SK*HD
    ushort_t* nmean = hmid + (size_t)SK * HD;        // N*HD
    ushort_t* nz    = nmean + (size_t)N * HD;        // N*HD
    ushort_t* nmid  = nz + (size_t)N * HD;           // N*HD
    ushort_t* h2    = nmid + (size_t)N * HD;         // N*HD
    ushort_t* rootm = h2 + (size_t)N * HD;           // N*HD
    ushort_t* wbuf  = rootm + (size_t)N * HD;        // 7*L*16384
    float* fp = (float*)(wbuf + (size_t)7 * L * 16384);
    float* vf  = fp;                                 // SK
    float* cb  = vf + SK;                            // L*128
    float* b2g = cb + (size_t)L * 128;               // L*128
    int* ip = (int*)(b2g + (size_t)L * 128);
    int* degI   = ip;
    int* degG   = degI + SK;
    int* degN   = degG + N;
    int* degR   = degN + N;
    int* startI = degR + N;
    int* startG = startI + SK + 1;
    int* startN = startG + N + 1;
    int* startR = startN + N + 1;
    int* slotI  = startR + N + 1;
    int* slotG  = slotI + EI;
    int* slotN  = slotG + EG;
    int* slotR  = slotN + SK;

    const int B = 256;
    const int gwSK = (SK * 64 + B - 1) / B;     // wave-per-row, SK rows
    const int gwN  = (N * 64 + B - 1) / B;      // wave-per-row, N rows
    const int gmSK = (SK + 63) / 64;            // mfma blocks
    const int gmN  = (N + 63) / 64;
    const int* intra_dst = intra_ei + EI;
    const int* glob_dst  = edge_index + EG;

    // ---- weight/bias prep ----
    int wtot = 7 * L * 16384;
    k_convert_w<<<(wtot + B - 1) / B, B, 0, stream>>>(lW1, lW2, gW1, gW2, skipW,
            vvW, kkW, lbn_g, gbn_g, wbuf, L);
    k_bias<<<(L * 128 + B - 1) / B, B, 0, stream>>>(lb2, lbn_g, lbn_b, skipb, vvb,
            kkb, gb2, gbn_g, gbn_b, cb, b2g, L * 128);

    // ---- CSR build ----
    hipMemsetAsync(degI, 0, (size_t)(SK + 3 * N) * sizeof(int), stream);
    k_hist<<<(EI + B - 1) / B, B, 0, stream>>>(intra_dst, degI, EI, 1);
    k_hist<<<(EG + B - 1) / B, B, 0, stream>>>(glob_dst, degG, EG, 1);
    k_hist<<<(SK + B - 1) / B, B, 0, stream>>>(node_ids, degN, SK, 1);
    k_hist<<<(S + B - 1) / B, B, 0, stream>>>(node_ids, degR, S, 16);
    k_scan4<<<4, 1024, 0, stream>>>(degI, startI, SK, degG, startG, N,
                                    degN, startN, N, degR, startR, N);
    hipMemsetAsync(degI, 0, (size_t)(SK + 3 * N) * sizeof(int), stream);
    k_fill<<<(EI + B - 1) / B, B, 0, stream>>>(intra_dst, startI, degI, slotI, EI, 1, 0);
    k_fill<<<(EG + B - 1) / B, B, 0, stream>>>(glob_dst, startG, degG, slotG, EG, 1, 0);
    k_fill<<<(SK + B - 1) / B, B, 0, stream>>>(node_ids, startN, degN, slotN, SK, 1, 0);
    k_fill<<<(S + B - 1) / B, B, 0, stream>>>(node_ids, startR, degR, slotR, S, 16, 1);

    // ---- init ----
    k_vf<<<(SK + B - 1) / B, B, 0, stream>>>(node_ids, vf, SK);
    k_init_h<<<gwSK, B, 0, stream>>>(atom_table, role_table, atom_ids, vf, hA, SK);

    ushort_t* hcur = hA;
    ushort_t* zb   = hB;
    auto WB = [&](int fam, int l) { return wbuf + ((size_t)(fam * L + l)) * 16384; };

    for (int l = 0; l < L; ++l) {
        const size_t lb = (size_t)l * HD;
        // 1) zb = hcur + intra-GINE agg
        k_gine_z<<<gwSK, B, 0, stream>>>(hcur, intra_ei, bond_ids_intra, bond_table,
                                         startI, slotI, zb, SK);
        // 2) hmid = relu(zb @ lW1^T + lb1)
        k_mfma1<<<gmSK, B, 0, stream>>>(zb, WB(0, l), lb1 + lb, hmid, SK, 1);
        // 3) nmean = seg_mean(hcur, node CSR)
        k_segmean<<<gwN, B, 0, stream>>>(hcur, startN, slotN, nmean, N);
        // 4) nz = nmean + global-GINE agg
        k_gine_z<<<gwN, B, 0, stream>>>(nmean, edge_index, bond_ids_global, bond_table,
                                        startG, slotG, nz, N);
        // 5) nmid = relu(nz @ gW1^T + gb1)
        k_mfma1<<<gmN, B, 0, stream>>>(nz, WB(2, l), gb1 + lb, nmid, N, 1);
        // 6) h2 = nmid @ (gW2*gbn_g)^T + (gb2*gbn_g + gbn_b)
        k_mfma1<<<gmN, B, 0, stream>>>(nmid, WB(3, l), b2g + lb, h2, N, 0);
        // 7) rootm = root seg_mean(hcur)
        k_segmean<<<gwN, B, 0, stream>>>(hcur, startR, slotR, rootm, N);
        // 8) zb = relu(hmid@W2g + hcur@skipW + rootm[c]@vvW + hcur[root]@kkW + h2[c] + cb)*vf
        k_mfma_fused<<<gmSK, B, 0, stream>>>(hmid, hcur, rootm, h2, node_ids, vf,
                WB(1, l), WB(4, l), WB(5, l), WB(6, l), cb + lb, zb, SK);
        // swap: zb becomes the new h
        ushort_t* tmp = hcur; hcur = zb; zb = tmp;
    }

    // final: node_embs = seg_mean(hcur); out = segment_sum(node_embs, batch)
    k_segmean<<<gwN, B, 0, stream>>>(hcur, startN, slotN, nmean, N);
    hipMemsetAsync(d_out, 0, (size_t)out_size * sizeof(float), stream);
    k_pool<<<gwN, B, 0, stream>>>(nmean, batch, (float*)d_out, N);
}

// Round 5
// 1563.283 us; speedup vs baseline: 7.9653x; 1.2697x over previous
//
#include <hip/hip_runtime.h>

typedef unsigned short ushort_t;
typedef unsigned int uint_t;
typedef __attribute__((ext_vector_type(8))) short v8s;   // 8 bf16 (4 VGPRs) MFMA A/B frag
typedef __attribute__((ext_vector_type(4))) float v4f;   // MFMA C/D frag

#define HD 128
#define MFMA16(a, b, c) __builtin_amdgcn_mfma_f32_16x16x32_bf16((a), (b), (c), 0, 0, 0)

__device__ __forceinline__ float b2f(ushort_t u) {
    union { uint_t i; float f; } v; v.i = ((uint_t)u) << 16; return v.f;
}
__device__ __forceinline__ ushort_t f2b(float f) {
    union { float f; uint_t i; } v; v.f = f;
    uint_t u = v.i;
    return (ushort_t)((u + 0x7FFFu + ((u >> 16) & 1u)) >> 16);
}

// ================= CSR build =================

__global__ __launch_bounds__(256) void k_hist(const int* __restrict__ ids,
        int* __restrict__ deg, int M, int stride) {
    int i = blockIdx.x * blockDim.x + threadIdx.x;
    if (i >= M) return;
    int id = ids[(size_t)i * stride];
    if (id >= 0) atomicAdd(&deg[id], 1);
}

__global__ __launch_bounds__(1024) void k_scan4(
        const int* d0, int* s0, int n0, const int* d1, int* s1, int n1,
        const int* d2, int* s2, int n2, const int* d3, int* s3, int n3) {
    const int* d; int* s; int n;
    if (blockIdx.x == 0)      { d = d0; s = s0; n = n0; }
    else if (blockIdx.x == 1) { d = d1; s = s1; n = n1; }
    else if (blockIdx.x == 2) { d = d2; s = s2; n = n2; }
    else                      { d = d3; s = s3; n = n3; }
    __shared__ int wsum[16];
    int t = threadIdx.x, lane = t & 63, w = t >> 6;
    int carry = 0;
    for (int base = 0; base < n; base += 1024) {
        int i = base + t;
        int v = (i < n) ? d[i] : 0;
        int x = v;
        #pragma unroll
        for (int off = 1; off < 64; off <<= 1) {
            int y = __shfl_up(x, off);
            if (lane >= off) x += y;
        }
        if (lane == 63) wsum[w] = x;
        __syncthreads();
        int wo = 0, tot = 0;
        #pragma unroll
        for (int ww = 0; ww < 16; ++ww) {
            int sv = wsum[ww];
            if (ww < w) wo += sv;
            tot += sv;
        }
        if (i < n) s[i] = carry + wo + (x - v);
        carry += tot;
        __syncthreads();
    }
    if (t == 0) s[n] = carry;
}

// node/root CSR fill: slots[pos] = i*stride (row index)
__global__ __launch_bounds__(256) void k_fill(const int* __restrict__ ids,
        const int* __restrict__ start, int* __restrict__ cursor,
        int* __restrict__ slots, int M, int stride) {
    int i = blockIdx.x * blockDim.x + threadIdx.x;
    if (i >= M) return;
    int id = ids[(size_t)i * stride];
    if (id < 0) return;
    int pos = start[id] + atomicAdd(&cursor[id], 1);
    slots[pos] = i * stride;
}

// edge CSR fill: slots[pos] = src | (bid << 20)  (src < 2^20, bid < 16)
__global__ __launch_bounds__(256) void k_fill_edges(const int* __restrict__ dst,
        const int* __restrict__ src, const int* __restrict__ bids,
        const int* __restrict__ start, int* __restrict__ cursor,
        int* __restrict__ slots, int E) {
    int e = blockIdx.x * blockDim.x + threadIdx.x;
    if (e >= E) return;
    int d = dst[e];
    if (d < 0) return;
    int pos = start[d] + atomicAdd(&cursor[d], 1);
    slots[pos] = src[e] | (bids[e] << 20);
}

// ================= weight/bias prep =================

// wbuf[(fam*L+l)*16384 + n*128 + k] = bf16( src_fam[l][n][k] * scale_fam[n] )
__global__ __launch_bounds__(256) void k_convert_w(
        const float* lW1, const float* lW2, const float* gW1, const float* gW2,
        const float* skipW, const float* vvW, const float* kkW,
        const float* lbn_g, const float* gbn_g,
        ushort_t* __restrict__ wbuf, int L) {
    int idx = blockIdx.x * blockDim.x + threadIdx.x;
    int total = 7 * L * 16384;
    if (idx >= total) return;
    int fam = idx / (L * 16384);
    int r = idx % (L * 16384);
    int l = r / 16384, e = r % 16384, n = e / 128;
    const float* src;
    float sc = 1.0f;
    switch (fam) {
        case 0: src = lW1; break;
        case 1: src = lW2; sc = lbn_g[l * 128 + n]; break;
        case 2: src = gW1; break;
        case 3: src = gW2; sc = gbn_g[l * 128 + n]; break;
        case 4: src = skipW; break;
        case 5: src = vvW; break;
        default: src = kkW; break;
    }
    wbuf[idx] = f2b(src[(size_t)l * 16384 + e] * sc);
}

__global__ __launch_bounds__(256) void k_bias(
        const float* lb2, const float* lbn_g, const float* lbn_b,
        const float* skipb, const float* vvb, const float* kkb,
        const float* gb2, const float* gbn_g, const float* gbn_b,
        float* __restrict__ cb, float* __restrict__ b2g, int total) {
    int i = blockIdx.x * blockDim.x + threadIdx.x;
    if (i >= total) return;
    cb[i] = lb2[i] * lbn_g[i] + lbn_b[i] + skipb[i] + vvb[i] + kkb[i];
    b2g[i] = gb2[i] * gbn_g[i] + gbn_b[i];
}

// ================= elementwise / graph kernels (bf16) =================

__global__ __launch_bounds__(256) void k_vf(const int* __restrict__ node_ids,
        float* __restrict__ vf, int SK) {
    int i = blockIdx.x * blockDim.x + threadIdx.x;
    if (i < SK) vf[i] = (node_ids[i] >= 0) ? 1.0f : 0.0f;
}

__global__ __launch_bounds__(256) void k_init_h(const float* __restrict__ at,
        const float* __restrict__ rt, const int* __restrict__ atom_ids,
        const float* __restrict__ vf, ushort_t* __restrict__ h, int SK) {
    int t = blockIdx.x * blockDim.x + threadIdx.x;
    int i = t >> 6, lane = t & 63;
    if (i >= SK) return;
    float2 a = ((const float2*)(at + (size_t)atom_ids[i] * HD))[lane];
    int role = ((i & 15) == 0) ? 1 : 0;
    float2 r = ((const float2*)(rt + (size_t)role * HD))[lane];
    float m = vf[i];
    uint_t o = (uint_t)f2b((a.x + r.x) * m) | ((uint_t)f2b((a.y + r.y) * m) << 16);
    *(uint_t*)(h + (size_t)i * HD + lane * 2) = o;
}

// outz[w] = X[w] + sum_p relu(X[src_p] + btab[bid_p]); slots pre-packed src|bid<<20
__global__ __launch_bounds__(256) void k_gine_z(const ushort_t* __restrict__ X,
        const float* __restrict__ btab, const int* __restrict__ start,
        const int* __restrict__ slots, ushort_t* __restrict__ outz, int Nrows) {
    int w = (blockIdx.x * 256 + threadIdx.x) >> 6;
    int lane = threadIdx.x & 63;
    if (w >= Nrows) return;
    int s0 = start[w], s1 = start[w + 1];
    uint_t xb = *(const uint_t*)(X + (size_t)w * HD + lane * 2);
    float ax = b2f((ushort_t)(xb & 0xFFFF)), ay = b2f((ushort_t)(xb >> 16));
    const float2* bt = (const float2*)btab;
    int p = s0;
    for (; p + 3 < s1; p += 4) {
        uint_t e0 = slots[p], e1 = slots[p + 1], e2 = slots[p + 2], e3 = slots[p + 3];
        uint_t u0 = *(const uint_t*)(X + (size_t)(e0 & 0xFFFFF) * HD + lane * 2);
        uint_t u1 = *(const uint_t*)(X + (size_t)(e1 & 0xFFFFF) * HD + lane * 2);
        uint_t u2 = *(const uint_t*)(X + (size_t)(e2 & 0xFFFFF) * HD + lane * 2);
        uint_t u3 = *(const uint_t*)(X + (size_t)(e3 & 0xFFFFF) * HD + lane * 2);
        float2 b0 = bt[(e0 >> 20) * 64 + lane];
        float2 b1 = bt[(e1 >> 20) * 64 + lane];
        float2 b2 = bt[(e2 >> 20) * 64 + lane];
        float2 b3 = bt[(e3 >> 20) * 64 + lane];
        ax += fmaxf(b2f((ushort_t)(u0 & 0xFFFF)) + b0.x, 0.f)
            + fmaxf(b2f((ushort_t)(u1 & 0xFFFF)) + b1.x, 0.f)
            + fmaxf(b2f((ushort_t)(u2 & 0xFFFF)) + b2.x, 0.f)
            + fmaxf(b2f((ushort_t)(u3 & 0xFFFF)) + b3.x, 0.f);
        ay += fmaxf(b2f((ushort_t)(u0 >> 16)) + b0.y, 0.f)
            + fmaxf(b2f((ushort_t)(u1 >> 16)) + b1.y, 0.f)
            + fmaxf(b2f((ushort_t)(u2 >> 16)) + b2.y, 0.f)
            + fmaxf(b2f((ushort_t)(u3 >> 16)) + b3.y, 0.f);
    }
    for (; p < s1; ++p) {
        uint_t e = slots[p];
        uint_t u = *(const uint_t*)(X + (size_t)(e & 0xFFFFF) * HD + lane * 2);
        float2 b = bt[(e >> 20) * 64 + lane];
        ax += fmaxf(b2f((ushort_t)(u & 0xFFFF)) + b.x, 0.f);
        ay += fmaxf(b2f((ushort_t)(u >> 16)) + b.y, 0.f);
    }
    uint_t o = (uint_t)f2b(ax) | ((uint_t)f2b(ay) << 16);
    *(uint_t*)(outz + (size_t)w * HD + lane * 2) = o;
}

// out[w] = mean of X rows listed in slots (bf16 in/out), unrolled x4
__global__ __launch_bounds__(256) void k_segmean(const ushort_t* __restrict__ X,
        const int* __restrict__ start, const int* __restrict__ slots,
        ushort_t* __restrict__ out, int Nrows) {
    int w = (blockIdx.x * 256 + threadIdx.x) >> 6;
    int lane = threadIdx.x & 63;
    if (w >= Nrows) return;
    int s0 = start[w], s1 = start[w + 1];
    float inv = 1.0f / fmaxf((float)(s1 - s0), 1.0f);
    float ax = 0.f, ay = 0.f;
    int p = s0;
    for (; p + 3 < s1; p += 4) {
        int r0 = slots[p], r1 = slots[p + 1], r2 = slots[p + 2], r3 = slots[p + 3];
        uint_t u0 = *(const uint_t*)(X + (size_t)r0 * HD + lane * 2);
        uint_t u1 = *(const uint_t*)(X + (size_t)r1 * HD + lane * 2);
        uint_t u2 = *(const uint_t*)(X + (size_t)r2 * HD + lane * 2);
        uint_t u3 = *(const uint_t*)(X + (size_t)r3 * HD + lane * 2);
        ax += b2f((ushort_t)(u0 & 0xFFFF)) + b2f((ushort_t)(u1 & 0xFFFF))
            + b2f((ushort_t)(u2 & 0xFFFF)) + b2f((ushort_t)(u3 & 0xFFFF));
        ay += b2f((ushort_t)(u0 >> 16)) + b2f((ushort_t)(u1 >> 16))
            + b2f((ushort_t)(u2 >> 16)) + b2f((ushort_t)(u3 >> 16));
    }
    for (; p < s1; ++p) {
        uint_t u = *(const uint_t*)(X + (size_t)slots[p] * HD + lane * 2);
        ax += b2f((ushort_t)(u & 0xFFFF));
        ay += b2f((ushort_t)(u >> 16));
    }
    uint_t o = (uint_t)f2b(ax * inv) | ((uint_t)f2b(ay * inv) << 16);
    *(uint_t*)(out + (size_t)w * HD + lane * 2) = o;
}

__global__ __launch_bounds__(256) void k_pool(const ushort_t* __restrict__ xsum,
        const int* __restrict__ batch, float* __restrict__ out, int N) {
    int t = blockIdx.x * blockDim.x + threadIdx.x;
    int n = t >> 6, lane = t & 63;
    if (n >= N) return;
    int g = batch[n];
    uint_t u = *(const uint_t*)(xsum + (size_t)n * HD + lane * 2);
    float* o = out + (size_t)g * HD + lane * 2;
    atomicAdd(o + 0, b2f((ushort_t)(u & 0xFFFF)));
    atomicAdd(o + 1, b2f((ushort_t)(u >> 16)));
}

// ================= MFMA GEMM: C = maybe_relu(A @ W^T + bias), bf16 =================
__global__ __launch_bounds__(256) void k_mfma1(const ushort_t* __restrict__ A,
        const ushort_t* __restrict__ Wb, const float* __restrict__ bias,
        ushort_t* __restrict__ C, int M, int relu_flag) {
    int lane = threadIdx.x & 63, wave = threadIdx.x >> 6;
    int row0 = (blockIdx.x * 4 + wave) * 16;
    if (row0 >= M) return;
    int m = lane & 15, quad = lane >> 4;
    int ar = row0 + m; if (ar > M - 1) ar = M - 1;
    const v8s* Ar = (const v8s*)(A + (size_t)ar * HD);
    v8s a0 = Ar[quad], a1 = Ar[4 + quad], a2 = Ar[8 + quad], a3 = Ar[12 + quad];
    int rbase = row0 + quad * 4;
    for (int nt = 0; nt < 8; ++nt) {
        const v8s* Wr = (const v8s*)(Wb + (size_t)(nt * 16 + m) * HD);
        v4f acc = {0.f, 0.f, 0.f, 0.f};
        acc = MFMA16(a0, Wr[quad], acc);
        acc = MFMA16(a1, Wr[4 + quad], acc);
        acc = MFMA16(a2, Wr[8 + quad], acc);
        acc = MFMA16(a3, Wr[12 + quad], acc);
        int col = nt * 16 + m;
        float bc = bias[col];
        #pragma unroll
        for (int r = 0; r < 4; ++r) {
            int row = rbase + r;
            if (row < M) {
                float v = acc[r] + bc;
                if (relu_flag) v = fmaxf(v, 0.f);
                C[(size_t)row * HD + col] = f2b(v);
            }
        }
    }
}

// ================= fused tail =================
__global__ __launch_bounds__(256) void k_mfma_fused(
        const ushort_t* __restrict__ hmid, const ushort_t* __restrict__ h,
        const ushort_t* __restrict__ rootm, const ushort_t* __restrict__ h2,
        const int* __restrict__ node_ids, const float* __restrict__ vf,
        const ushort_t* __restrict__ W2g, const ushort_t* __restrict__ Wsk,
        const ushort_t* __restrict__ Wvv, const ushort_t* __restrict__ Wkk,
        const float* __restrict__ cb, ushort_t* __restrict__ hout, int M) {
    int lane = threadIdx.x & 63, wave = threadIdx.x >> 6;
    int row0 = (blockIdx.x * 4 + wave) * 16;
    if (row0 >= M) return;
    int m = lane & 15, quad = lane >> 4;
    int ar = row0 + m;
    int nid = node_ids[ar]; int nc = nid > 0 ? nid : 0;
    const v8s* A0 = (const v8s*)(hmid + (size_t)ar * HD);
    const v8s* A1 = (const v8s*)(h + (size_t)ar * HD);
    const v8s* A2 = (const v8s*)(rootm + (size_t)nc * HD);
    const v8s* A3 = (const v8s*)(h + (size_t)(ar & ~15) * HD);
    v8s f0[4], f1[4], f2[4], f3[4];
    #pragma unroll
    for (int c = 0; c < 4; ++c) {
        f0[c] = A0[c * 4 + quad]; f1[c] = A1[c * 4 + quad];
        f2[c] = A2[c * 4 + quad]; f3[c] = A3[c * 4 + quad];
    }
    int nidr[4]; float vfr[4];
    #pragma unroll
    for (int r = 0; r < 4; ++r) {
        int row = row0 + quad * 4 + r;
        int q = node_ids[row];
        nidr[r] = q > 0 ? q : 0;
        vfr[r] = vf[row];
    }
    for (int nt = 0; nt < 8; ++nt) {
        int wr = nt * 16 + m;
        const v8s* W0 = (const v8s*)(W2g + (size_t)wr * HD);
        const v8s* W1 = (const v8s*)(Wsk + (size_t)wr * HD);
        const v8s* W2 = (const v8s*)(Wvv + (size_t)wr * HD);
        const v8s* W3 = (const v8s*)(Wkk + (size_t)wr * HD);
        v4f acc = {0.f, 0.f, 0.f, 0.f};
        #pragma unroll
        for (int c = 0; c < 4; ++c) {
            acc = MFMA16(f0[c], W0[c * 4 + quad], acc);
            acc = MFMA16(f1[c], W1[c * 4 + quad], acc);
            acc = MFMA16(f2[c], W2[c * 4 + quad], acc);
            acc = MFMA16(f3[c], W3[c * 4 + quad], acc);
        }
        int col = nt * 16 + m;
        float bc = cb[col];
        #pragma unroll
        for (int r = 0; r < 4; ++r) {
            int row = row0 + quad * 4 + r;
            float v = acc[r] + bc + b2f(h2[(size_t)nidr[r] * HD + col]);
            v = fmaxf(v, 0.f) * vfr[r];
            hout[(size_t)row * HD + col] = f2b(v);
        }
    }
}

// ================= launcher =================

extern "C" void kernel_launch(void* const* d_in, const int* in_sizes, int n_in,
                              void* d_out, int out_size, void* d_ws, size_t ws_size,
                              hipStream_t stream) {
    (void)n_in; (void)ws_size;
    const float* atom_table = (const float*)d_in[0];
    const float* bond_table = (const float*)d_in[1];
    const float* role_table = (const float*)d_in[2];
    const float* lW1 = (const float*)d_in[3];
    const float* lb1 = (const float*)d_in[4];
    const float* lW2 = (const float*)d_in[5];
    const float* lb2 = (const float*)d_in[6];
    const float* gW1 = (const float*)d_in[7];
    const float* gb1 = (const float*)d_in[8];
    const float* gW2 = (const float*)d_in[9];
    const float* gb2 = (const float*)d_in[10];
    const float* lbn_g = (const float*)d_in[11];
    const float* lbn_b = (const float*)d_in[12];
    const float* gbn_g = (const float*)d_in[13];
    const float* gbn_b = (const float*)d_in[14];
    const float* skipW = (const float*)d_in[15];
    const float* skipb = (const float*)d_in[16];
    const float* vvW = (const float*)d_in[17];
    const float* vvb = (const float*)d_in[18];
    const float* kkW = (const float*)d_in[19];
    const float* kkb = (const float*)d_in[20];
    const int* atom_ids = (const int*)d_in[21];
    const int* bond_ids_intra = (const int*)d_in[22];
    const int* bond_ids_global = (const int*)d_in[23];
    const int* intra_ei = (const int*)d_in[24];
    const int* node_ids = (const int*)d_in[25];
    const int* edge_index = (const int*)d_in[26];
    const int* batch = (const int*)d_in[28];

    const int SK = in_sizes[21];
    const int EI = in_sizes[22];
    const int EG = in_sizes[23];
    const int N  = in_sizes[28];
    const int L  = in_sizes[4] / HD;
    const int S  = SK / 16;

    // ---- workspace layout ----
    ushort_t* us = (ushort_t*)d_ws;
    ushort_t* hA    = us;
    ushort_t* hB    = hA + (size_t)SK * HD;
    ushort_t* hmid  = hB + (size_t)SK * HD;
    ushort_t* nmean = hmid + (size_t)SK * HD;
    ushort_t* nz    = nmean + (size_t)N * HD;
    ushort_t* nmid  = nz + (size_t)N * HD;
    ushort_t* h2    = nmid + (size_t)N * HD;
    ushort_t* rootm = h2 + (size_t)N * HD;
    ushort_t* wbuf  = rootm + (size_t)N * HD;
    float* fp = (float*)(wbuf + (size_t)7 * L * 16384);
    float* vf  = fp;
    float* cb  = vf + SK;
    float* b2g = cb + (size_t)L * 128;
    int* ip = (int*)(b2g + (size_t)L * 128);
    int* degI   = ip;
    int* degG   = degI + SK;
    int* degN   = degG + N;
    int* degR   = degN + N;
    int* startI = degR + N;
    int* startG = startI + SK + 1;
    int* startN = startG + N + 1;
    int* startR = startN + N + 1;
    int* slotI  = startR + N + 1;
    int* slotG  = slotI + EI;
    int* slotN  = slotG + EG;
    int* slotR  = slotN + SK;

    const int B = 256;
    const int gwSK = (SK * 64 + B - 1) / B;
    const int gwN  = (N * 64 + B - 1) / B;
    const int gmSK = (SK + 63) / 64;
    const int gmN  = (N + 63) / 64;
    const int* intra_src = intra_ei;
    const int* intra_dst = intra_ei + EI;
    const int* glob_src  = edge_index;
    const int* glob_dst  = edge_index + EG;

    // ---- weight/bias prep ----
    int wtot = 7 * L * 16384;
    k_convert_w<<<(wtot + B - 1) / B, B, 0, stream>>>(lW1, lW2, gW1, gW2, skipW,
            vvW, kkW, lbn_g, gbn_g, wbuf, L);
    k_bias<<<(L * 128 + B - 1) / B, B, 0, stream>>>(lb2, lbn_g, lbn_b, skipb, vvb,
            kkb, gb2, gbn_g, gbn_b, cb, b2g, L * 128);

    // ---- CSR build ----
    hipMemsetAsync(degI, 0, (size_t)(SK + 3 * N) * sizeof(int), stream);
    k_hist<<<(EI + B - 1) / B, B, 0, stream>>>(intra_dst, degI, EI, 1);
    k_hist<<<(EG + B - 1) / B, B, 0, stream>>>(glob_dst, degG, EG, 1);
    k_hist<<<(SK + B - 1) / B, B, 0, stream>>>(node_ids, degN, SK, 1);
    k_hist<<<(S + B - 1) / B, B, 0, stream>>>(node_ids, degR, S, 16);
    k_scan4<<<4, 1024, 0, stream>>>(degI, startI, SK, degG, startG, N,
                                    degN, startN, N, degR, startR, N);
    hipMemsetAsync(degI, 0, (size_t)(SK + 3 * N) * sizeof(int), stream);
    k_fill_edges<<<(EI + B - 1) / B, B, 0, stream>>>(intra_dst, intra_src,
            bond_ids_intra, startI, degI, slotI, EI);
    k_fill_edges<<<(EG + B - 1) / B, B, 0, stream>>>(glob_dst, glob_src,
            bond_ids_global, startG, degG, slotG, EG);
    k_fill<<<(SK + B - 1) / B, B, 0, stream>>>(node_ids, startN, degN, slotN, SK, 1);
    k_fill<<<(S + B - 1) / B, B, 0, stream>>>(node_ids, startR, degR, slotR, S, 16);

    // ---- init ----
    k_vf<<<(SK + B - 1) / B, B, 0, stream>>>(node_ids, vf, SK);
    k_init_h<<<gwSK, B, 0, stream>>>(atom_table, role_table, atom_ids, vf, hA, SK);

    ushort_t* hcur = hA;
    ushort_t* zb   = hB;
    auto WB = [&](int fam, int l) { return wbuf + ((size_t)(fam * L + l)) * 16384; };

    for (int l = 0; l < L; ++l) {
        const size_t lb = (size_t)l * HD;
        // 1) zb = hcur + intra-GINE agg
        k_gine_z<<<gwSK, B, 0, stream>>>(hcur, bond_table, startI, slotI, zb, SK);
        // 2) hmid = relu(zb @ lW1^T + lb1)
        k_mfma1<<<gmSK, B, 0, stream>>>(zb, WB(0, l), lb1 + lb, hmid, SK, 1);
        // 3) nmean = seg_mean(hcur, node CSR)
        k_segmean<<<gwN, B, 0, stream>>>(hcur, startN, slotN, nmean, N);
        // 4) nz = nmean + global-GINE agg
        k_gine_z<<<gwN, B, 0, stream>>>(nmean, bond_table, startG, slotG, nz, N);
        // 5) nmid = relu(nz @ gW1^T + gb1)
        k_mfma1<<<gmN, B, 0, stream>>>(nz, WB(2, l), gb1 + lb, nmid, N, 1);
        // 6) h2 = nmid @ (gW2*gbn_g)^T + (gb2*gbn_g + gbn_b)
        k_mfma1<<<gmN, B, 0, stream>>>(nmid, WB(3, l), b2g + lb, h2, N, 0);
        // 7) rootm = root seg_mean(hcur)
        k_segmean<<<gwN, B, 0, stream>>>(hcur, startR, slotR, rootm, N);
        // 8) fused tail -> zb
        k_mfma_fused<<<gmSK, B, 0, stream>>>(hmid, hcur, rootm, h2, node_ids, vf,
                WB(1, l), WB(4, l), WB(5, l), WB(6, l), cb + lb, zb, SK);
        ushort_t* tmp = hcur; hcur = zb; zb = tmp;
    }

    // final: node_embs = seg_mean(hcur); out = segment_sum(node_embs, batch)
    k_segmean<<<gwN, B, 0, stream>>>(hcur, startN, slotN, nmean, N);
    hipMemsetAsync(d_out, 0, (size_t)out_size * sizeof(float), stream);
    k_pool<<<gwN, B, 0, stream>>>(nmean, batch, (float*)d_out, N);
}

// Round 6
// 1159.660 us; speedup vs baseline: 10.7377x; 1.3481x over previous
//
#include <hip/hip_runtime.h>

typedef unsigned short ushort_t;
typedef unsigned int uint_t;
typedef __attribute__((ext_vector_type(8))) short v8s;   // 8 bf16 MFMA A/B frag
typedef __attribute__((ext_vector_type(4))) float v4f;   // MFMA C/D frag

#define HD 128
#define LSTR 136   // LDS weight row stride in shorts (272 B: 16B-aligned, 2-way-max conflicts)
#define MFMA16(a, b, c) __builtin_amdgcn_mfma_f32_16x16x32_bf16((a), (b), (c), 0, 0, 0)

__device__ __forceinline__ float b2f(ushort_t u) {
    union { uint_t i; float f; } v; v.i = ((uint_t)u) << 16; return v.f;
}
__device__ __forceinline__ ushort_t f2b(float f) {
    union { float f; uint_t i; } v; v.f = f;
    uint_t u = v.i;
    return (ushort_t)((u + 0x7FFFu + ((u >> 16) & 1u)) >> 16);
}

// ================= CSR build =================

__global__ __launch_bounds__(256) void k_hist(const int* __restrict__ ids,
        int* __restrict__ deg, int M, int stride) {
    int i = blockIdx.x * blockDim.x + threadIdx.x;
    if (i >= M) return;
    int id = ids[(size_t)i * stride];
    if (id >= 0) atomicAdd(&deg[id], 1);
}

__global__ __launch_bounds__(1024) void k_scan4(
        const int* d0, int* s0, int n0, const int* d1, int* s1, int n1,
        const int* d2, int* s2, int n2, const int* d3, int* s3, int n3) {
    const int* d; int* s; int n;
    if (blockIdx.x == 0)      { d = d0; s = s0; n = n0; }
    else if (blockIdx.x == 1) { d = d1; s = s1; n = n1; }
    else if (blockIdx.x == 2) { d = d2; s = s2; n = n2; }
    else                      { d = d3; s = s3; n = n3; }
    __shared__ int wsum[16];
    int t = threadIdx.x, lane = t & 63, w = t >> 6;
    int carry = 0;
    for (int base = 0; base < n; base += 1024) {
        int i = base + t;
        int v = (i < n) ? d[i] : 0;
        int x = v;
        #pragma unroll
        for (int off = 1; off < 64; off <<= 1) {
            int y = __shfl_up(x, off);
            if (lane >= off) x += y;
        }
        if (lane == 63) wsum[w] = x;
        __syncthreads();
        int wo = 0, tot = 0;
        #pragma unroll
        for (int ww = 0; ww < 16; ++ww) {
            int sv = wsum[ww];
            if (ww < w) wo += sv;
            tot += sv;
        }
        if (i < n) s[i] = carry + wo + (x - v);
        carry += tot;
        __syncthreads();
    }
    if (t == 0) s[n] = carry;
}

__global__ __launch_bounds__(256) void k_fill(const int* __restrict__ ids,
        const int* __restrict__ start, int* __restrict__ cursor,
        int* __restrict__ slots, int M, int stride) {
    int i = blockIdx.x * blockDim.x + threadIdx.x;
    if (i >= M) return;
    int id = ids[(size_t)i * stride];
    if (id < 0) return;
    int pos = start[id] + atomicAdd(&cursor[id], 1);
    slots[pos] = i * stride;
}

// edge CSR fill: slots[pos] = src | (bid << 20)
__global__ __launch_bounds__(256) void k_fill_edges(const int* __restrict__ dst,
        const int* __restrict__ src, const int* __restrict__ bids,
        const int* __restrict__ start, int* __restrict__ cursor,
        int* __restrict__ slots, int E) {
    int e = blockIdx.x * blockDim.x + threadIdx.x;
    if (e >= E) return;
    int d = dst[e];
    if (d < 0) return;
    int pos = start[d] + atomicAdd(&cursor[d], 1);
    slots[pos] = src[e] | (bids[e] << 20);
}

// ================= weight/bias prep =================

__global__ __launch_bounds__(256) void k_convert_w(
        const float* lW1, const float* lW2, const float* gW1, const float* gW2,
        const float* skipW, const float* vvW, const float* kkW,
        const float* lbn_g, const float* gbn_g,
        ushort_t* __restrict__ wbuf, int L) {
    int idx = blockIdx.x * blockDim.x + threadIdx.x;
    int total = 7 * L * 16384;
    if (idx >= total) return;
    int fam = idx / (L * 16384);
    int r = idx % (L * 16384);
    int l = r / 16384, e = r % 16384, n = e / 128;
    const float* src;
    float sc = 1.0f;
    switch (fam) {
        case 0: src = lW1; break;
        case 1: src = lW2; sc = lbn_g[l * 128 + n]; break;
        case 2: src = gW1; break;
        case 3: src = gW2; sc = gbn_g[l * 128 + n]; break;
        case 4: src = skipW; break;
        case 5: src = vvW; break;
        default: src = kkW; break;
    }
    wbuf[idx] = f2b(src[(size_t)l * 16384 + e] * sc);
}

__global__ __launch_bounds__(256) void k_bias(
        const float* lb2, const float* lbn_g, const float* lbn_b,
        const float* skipb, const float* vvb, const float* kkb,
        const float* gb2, const float* gbn_g, const float* gbn_b,
        float* __restrict__ cb, float* __restrict__ b2g, int total) {
    int i = blockIdx.x * blockDim.x + threadIdx.x;
    if (i >= total) return;
    cb[i] = lb2[i] * lbn_g[i] + lbn_b[i] + skipb[i] + vvb[i] + kkb[i];
    b2g[i] = gb2[i] * gbn_g[i] + gbn_b[i];
}

// ================= elementwise / graph kernels (bf16) =================

__global__ __launch_bounds__(256) void k_vf(const int* __restrict__ node_ids,
        float* __restrict__ vf, int SK) {
    int i = blockIdx.x * blockDim.x + threadIdx.x;
    if (i < SK) vf[i] = (node_ids[i] >= 0) ? 1.0f : 0.0f;
}

__global__ __launch_bounds__(256) void k_init_h(const float* __restrict__ at,
        const float* __restrict__ rt, const int* __restrict__ atom_ids,
        const float* __restrict__ vf, ushort_t* __restrict__ h, int SK) {
    int t = blockIdx.x * blockDim.x + threadIdx.x;
    int i = t >> 6, lane = t & 63;
    if (i >= SK) return;
    float2 a = ((const float2*)(at + (size_t)atom_ids[i] * HD))[lane];
    int role = ((i & 15) == 0) ? 1 : 0;
    float2 r = ((const float2*)(rt + (size_t)role * HD))[lane];
    float m = vf[i];
    uint_t o = (uint_t)f2b((a.x + r.x) * m) | ((uint_t)f2b((a.y + r.y) * m) << 16);
    *(uint_t*)(h + (size_t)i * HD + lane * 2) = o;
}

// outz[w] = X[w] + sum_p relu(X[src_p] + btab[bid_p]); slots packed src|bid<<20
__global__ __launch_bounds__(256) void k_gine_z(const ushort_t* __restrict__ X,
        const float* __restrict__ btab, const int* __restrict__ start,
        const int* __restrict__ slots, ushort_t* __restrict__ outz, int Nrows) {
    int w = (blockIdx.x * 256 + threadIdx.x) >> 6;
    int lane = threadIdx.x & 63;
    if (w >= Nrows) return;
    int s0 = start[w], s1 = start[w + 1];
    uint_t xb = *(const uint_t*)(X + (size_t)w * HD + lane * 2);
    float ax = b2f((ushort_t)(xb & 0xFFFF)), ay = b2f((ushort_t)(xb >> 16));
    const float2* bt = (const float2*)btab;
    int p = s0;
    for (; p + 7 < s1; p += 8) {
        uint_t e[8], u[8]; float2 bb[8];
        #pragma unroll
        for (int j = 0; j < 8; ++j) e[j] = slots[p + j];
        #pragma unroll
        for (int j = 0; j < 8; ++j) {
            u[j] = *(const uint_t*)(X + (size_t)(e[j] & 0xFFFFF) * HD + lane * 2);
            bb[j] = bt[(e[j] >> 20) * 64 + lane];
        }
        #pragma unroll
        for (int j = 0; j < 8; ++j) {
            ax += fmaxf(b2f((ushort_t)(u[j] & 0xFFFF)) + bb[j].x, 0.f);
            ay += fmaxf(b2f((ushort_t)(u[j] >> 16)) + bb[j].y, 0.f);
        }
    }
    for (; p + 3 < s1; p += 4) {
        uint_t e[4], u[4]; float2 bb[4];
        #pragma unroll
        for (int j = 0; j < 4; ++j) e[j] = slots[p + j];
        #pragma unroll
        for (int j = 0; j < 4; ++j) {
            u[j] = *(const uint_t*)(X + (size_t)(e[j] & 0xFFFFF) * HD + lane * 2);
            bb[j] = bt[(e[j] >> 20) * 64 + lane];
        }
        #pragma unroll
        for (int j = 0; j < 4; ++j) {
            ax += fmaxf(b2f((ushort_t)(u[j] & 0xFFFF)) + bb[j].x, 0.f);
            ay += fmaxf(b2f((ushort_t)(u[j] >> 16)) + bb[j].y, 0.f);
        }
    }
    for (; p < s1; ++p) {
        uint_t e = slots[p];
        uint_t u = *(const uint_t*)(X + (size_t)(e & 0xFFFFF) * HD + lane * 2);
        float2 b = bt[(e >> 20) * 64 + lane];
        ax += fmaxf(b2f((ushort_t)(u & 0xFFFF)) + b.x, 0.f);
        ay += fmaxf(b2f((ushort_t)(u >> 16)) + b.y, 0.f);
    }
    uint_t o = (uint_t)f2b(ax) | ((uint_t)f2b(ay) << 16);
    *(uint_t*)(outz + (size_t)w * HD + lane * 2) = o;
}

// out[w] = mean of X rows listed in slots
__global__ __launch_bounds__(256) void k_segmean(const ushort_t* __restrict__ X,
        const int* __restrict__ start, const int* __restrict__ slots,
        ushort_t* __restrict__ out, int Nrows) {
    int w = (blockIdx.x * 256 + threadIdx.x) >> 6;
    int lane = threadIdx.x & 63;
    if (w >= Nrows) return;
    int s0 = start[w], s1 = start[w + 1];
    float inv = 1.0f / fmaxf((float)(s1 - s0), 1.0f);
    float ax = 0.f, ay = 0.f;
    int p = s0;
    for (; p + 3 < s1; p += 4) {
        int r0 = slots[p], r1 = slots[p + 1], r2 = slots[p + 2], r3 = slots[p + 3];
        uint_t u0 = *(const uint_t*)(X + (size_t)r0 * HD + lane * 2);
        uint_t u1 = *(const uint_t*)(X + (size_t)r1 * HD + lane * 2);
        uint_t u2 = *(const uint_t*)(X + (size_t)r2 * HD + lane * 2);
        uint_t u3 = *(const uint_t*)(X + (size_t)r3 * HD + lane * 2);
        ax += b2f((ushort_t)(u0 & 0xFFFF)) + b2f((ushort_t)(u1 & 0xFFFF))
            + b2f((ushort_t)(u2 & 0xFFFF)) + b2f((ushort_t)(u3 & 0xFFFF));
        ay += b2f((ushort_t)(u0 >> 16)) + b2f((ushort_t)(u1 >> 16))
            + b2f((ushort_t)(u2 >> 16)) + b2f((ushort_t)(u3 >> 16));
    }
    for (; p < s1; ++p) {
        uint_t u = *(const uint_t*)(X + (size_t)slots[p] * HD + lane * 2);
        ax += b2f((ushort_t)(u & 0xFFFF));
        ay += b2f((ushort_t)(u >> 16));
    }
    uint_t o = (uint_t)f2b(ax * inv) | ((uint_t)f2b(ay * inv) << 16);
    *(uint_t*)(out + (size_t)w * HD + lane * 2) = o;
}

__global__ __launch_bounds__(256) void k_pool(const ushort_t* __restrict__ xsum,
        const int* __restrict__ batch, float* __restrict__ out, int N) {
    int t = blockIdx.x * blockDim.x + threadIdx.x;
    int n = t >> 6, lane = t & 63;
    if (n >= N) return;
    int g = batch[n];
    uint_t u = *(const uint_t*)(xsum + (size_t)n * HD + lane * 2);
    float* o = out + (size_t)g * HD + lane * 2;
    atomicAdd(o + 0, b2f((ushort_t)(u & 0xFFFF)));
    atomicAdd(o + 1, b2f((ushort_t)(u >> 16)));
}

// ---- shared helper: stage one 128x128 bf16 weight into padded LDS ----
__device__ __forceinline__ void stage_w(ushort_t* Wl, const ushort_t* Wb, int t) {
    #pragma unroll
    for (int it = 0; it < 8; ++it) {
        int idx = it * 256 + t;
        uint4 v = *(const uint4*)(Wb + (size_t)idx * 8);
        int row = idx >> 4, col = (idx & 15) * 8;
        *(uint4*)&Wl[row * LSTR + col] = v;
    }
}

// ================= GEMM: C = maybe_relu(A @ W^T + bias) =================
// Block = 64 rows (4 waves x 16). W staged in LDS (padded). Operand-swapped MFMA:
// lane holds output row (lane&15), cols nt*16 + quad*4 + r -> packed 8B stores.
__global__ __launch_bounds__(256) void k_gemm1(const ushort_t* __restrict__ A,
        const ushort_t* __restrict__ Wb, const float* __restrict__ bias,
        ushort_t* __restrict__ C, int M, int relu_flag) {
    __shared__ ushort_t Wl[128 * LSTR];
    const int t = threadIdx.x;
    stage_w(Wl, Wb, t);
    int lane = t & 63, wave = t >> 6;
    int m = lane & 15, quad = lane >> 4;
    int row = blockIdx.x * 64 + wave * 16 + m;
    int ar = row < M ? row : M - 1;
    const v8s* Ar = (const v8s*)(A + (size_t)ar * HD);
    v8s bfrag[4];
    #pragma unroll
    for (int c = 0; c < 4; ++c) bfrag[c] = Ar[c * 4 + quad];
    __syncthreads();
    v4f acc[8];
    #pragma unroll
    for (int nt = 0; nt < 8; ++nt) acc[nt] = (v4f){0.f, 0.f, 0.f, 0.f};
    #pragma unroll
    for (int nt = 0; nt < 8; ++nt) {
        #pragma unroll
        for (int c = 0; c < 4; ++c) {
            v8s wf = *(const v8s*)&Wl[(nt * 16 + m) * LSTR + c * 32 + quad * 8];
            acc[nt] = MFMA16(wf, bfrag[c], acc[nt]);
        }
    }
    if (row < M) {
        ushort_t* Cr = C + (size_t)row * HD;
        #pragma unroll
        for (int nt = 0; nt < 8; ++nt) {
            int col = nt * 16 + quad * 4;
            float4 b = *(const float4*)(bias + col);
            float v0 = acc[nt][0] + b.x, v1 = acc[nt][1] + b.y;
            float v2 = acc[nt][2] + b.z, v3 = acc[nt][3] + b.w;
            if (relu_flag) {
                v0 = fmaxf(v0, 0.f); v1 = fmaxf(v1, 0.f);
                v2 = fmaxf(v2, 0.f); v3 = fmaxf(v3, 0.f);
            }
            uint2 o;
            o.x = (uint_t)f2b(v0) | ((uint_t)f2b(v1) << 16);
            o.y = (uint_t)f2b(v2) | ((uint_t)f2b(v3) << 16);
            *(uint2*)(Cr + col) = o;
        }
    }
}

// ================= fused tail: hout = relu(hmid@W2g + h@Wsk + rootm[c]@Wvv
//                       + h[root]@Wkk + h2[c] + cb) * vf.  M multiple of 64. =================
__global__ __launch_bounds__(256) void k_gemm_fused(
        const ushort_t* __restrict__ hmid, const ushort_t* __restrict__ h,
        const ushort_t* __restrict__ rootm, const ushort_t* __restrict__ h2,
        const int* __restrict__ node_ids, const float* __restrict__ vf,
        const ushort_t* __restrict__ W2g, const ushort_t* __restrict__ Wsk,
        const ushort_t* __restrict__ Wvv, const ushort_t* __restrict__ Wkk,
        const float* __restrict__ cb, ushort_t* __restrict__ hout, int M) {
    __shared__ ushort_t Wl[128 * LSTR];
    const int t = threadIdx.x;
    int lane = t & 63, wave = t >> 6;
    int m = lane & 15, quad = lane >> 4;
    int row = blockIdx.x * 64 + wave * 16 + m;
    int nid = node_ids[row];
    int nc = nid > 0 ? nid : 0;
    const ushort_t* Asrc[4];
    Asrc[0] = hmid + (size_t)row * HD;
    Asrc[1] = h + (size_t)row * HD;
    Asrc[2] = rootm + (size_t)nc * HD;
    Asrc[3] = h + (size_t)(row & ~15) * HD;
    const ushort_t* Ws[4] = {W2g, Wsk, Wvv, Wkk};
    v4f acc[8];
    #pragma unroll
    for (int nt = 0; nt < 8; ++nt) acc[nt] = (v4f){0.f, 0.f, 0.f, 0.f};
    for (int ph = 0; ph < 4; ++ph) {
        if (ph) __syncthreads();   // previous-phase LDS reads done
        stage_w(Wl, Ws[ph], t);
        const v8s* Ar = (const v8s*)Asrc[ph];
        v8s bfrag[4];
        #pragma unroll
        for (int c = 0; c < 4; ++c) bfrag[c] = Ar[c * 4 + quad];
        __syncthreads();
        #pragma unroll
        for (int nt = 0; nt < 8; ++nt) {
            #pragma unroll
            for (int c = 0; c < 4; ++c) {
                v8s wf = *(const v8s*)&Wl[(nt * 16 + m) * LSTR + c * 32 + quad * 8];
                acc[nt] = MFMA16(wf, bfrag[c], acc[nt]);
            }
        }
    }
    float vfm = vf[row];
    const ushort_t* h2r = h2 + (size_t)nc * HD;
    ushort_t* Cr = hout + (size_t)row * HD;
    #pragma unroll
    for (int nt = 0; nt < 8; ++nt) {
        int col = nt * 16 + quad * 4;
        float4 b = *(const float4*)(cb + col);
        uint2 hh = *(const uint2*)(h2r + col);
        float v0 = acc[nt][0] + b.x + b2f((ushort_t)(hh.x & 0xFFFF));
        float v1 = acc[nt][1] + b.y + b2f((ushort_t)(hh.x >> 16));
        float v2 = acc[nt][2] + b.z + b2f((ushort_t)(hh.y & 0xFFFF));
        float v3 = acc[nt][3] + b.w + b2f((ushort_t)(hh.y >> 16));
        v0 = fmaxf(v0, 0.f) * vfm; v1 = fmaxf(v1, 0.f) * vfm;
        v2 = fmaxf(v2, 0.f) * vfm; v3 = fmaxf(v3, 0.f) * vfm;
        uint2 o;
        o.x = (uint_t)f2b(v0) | ((uint_t)f2b(v1) << 16);
        o.y = (uint_t)f2b(v2) | ((uint_t)f2b(v3) << 16);
        *(uint2*)(Cr + col) = o;
    }
}

// ================= launcher =================

extern "C" void kernel_launch(void* const* d_in, const int* in_sizes, int n_in,
                              void* d_out, int out_size, void* d_ws, size_t ws_size,
                              hipStream_t stream) {
    (void)n_in; (void)ws_size;
    const float* atom_table = (const float*)d_in[0];
    const float* bond_table = (const float*)d_in[1];
    const float* role_table = (const float*)d_in[2];
    const float* lW1 = (const float*)d_in[3];
    const float* lb1 = (const float*)d_in[4];
    const float* lW2 = (const float*)d_in[5];
    const float* lb2 = (const float*)d_in[6];
    const float* gW1 = (const float*)d_in[7];
    const float* gb1 = (const float*)d_in[8];
    const float* gW2 = (const float*)d_in[9];
    const float* gb2 = (const float*)d_in[10];
    const float* lbn_g = (const float*)d_in[11];
    const float* lbn_b = (const float*)d_in[12];
    const float* gbn_g = (const float*)d_in[13];
    const float* gbn_b = (const float*)d_in[14];
    const float* skipW = (const float*)d_in[15];
    const float* skipb = (const float*)d_in[16];
    const float* vvW = (const float*)d_in[17];
    const float* vvb = (const float*)d_in[18];
    const float* kkW = (const float*)d_in[19];
    const float* kkb = (const float*)d_in[20];
    const int* atom_ids = (const int*)d_in[21];
    const int* bond_ids_intra = (const int*)d_in[22];
    const int* bond_ids_global = (const int*)d_in[23];
    const int* intra_ei = (const int*)d_in[24];
    const int* node_ids = (const int*)d_in[25];
    const int* edge_index = (const int*)d_in[26];
    const int* batch = (const int*)d_in[28];

    const int SK = in_sizes[21];
    const int EI = in_sizes[22];
    const int EG = in_sizes[23];
    const int N  = in_sizes[28];
    const int L  = in_sizes[4] / HD;
    const int S  = SK / 16;

    // ---- workspace layout ----
    ushort_t* us = (ushort_t*)d_ws;
    ushort_t* hA    = us;
    ushort_t* hB    = hA + (size_t)SK * HD;
    ushort_t* hmid  = hB + (size_t)SK * HD;
    ushort_t* nmean = hmid + (size_t)SK * HD;
    ushort_t* nz    = nmean + (size_t)N * HD;
    ushort_t* nmid  = nz + (size_t)N * HD;
    ushort_t* h2    = nmid + (size_t)N * HD;
    ushort_t* rootm = h2 + (size_t)N * HD;
    ushort_t* wbuf  = rootm + (size_t)N * HD;
    float* fp = (float*)(wbuf + (size_t)7 * L * 16384);
    float* vf  = fp;
    float* cb  = vf + SK;
    float* b2g = cb + (size_t)L * 128;
    int* ip = (int*)(b2g + (size_t)L * 128);
    int* degI   = ip;
    int* degG   = degI + SK;
    int* degN   = degG + N;
    int* degR   = degN + N;
    int* startI = degR + N;
    int* startG = startI + SK + 1;
    int* startN = startG + N + 1;
    int* startR = startN + N + 1;
    int* slotI  = startR + N + 1;
    int* slotG  = slotI + EI;
    int* slotN  = slotG + EG;
    int* slotR  = slotN + SK;

    const int B = 256;
    const int gwSK = (SK * 64 + B - 1) / B;
    const int gwN  = (N * 64 + B - 1) / B;
    const int ggSK = (SK + 63) / 64;   // gemm blocks (64 rows each)
    const int ggN  = (N + 63) / 64;
    const int* intra_src = intra_ei;
    const int* intra_dst = intra_ei + EI;
    const int* glob_src  = edge_index;
    const int* glob_dst  = edge_index + EG;

    // ---- weight/bias prep ----
    int wtot = 7 * L * 16384;
    k_convert_w<<<(wtot + B - 1) / B, B, 0, stream>>>(lW1, lW2, gW1, gW2, skipW,
            vvW, kkW, lbn_g, gbn_g, wbuf, L);
    k_bias<<<(L * 128 + B - 1) / B, B, 0, stream>>>(lb2, lbn_g, lbn_b, skipb, vvb,
            kkb, gb2, gbn_g, gbn_b, cb, b2g, L * 128);

    // ---- CSR build ----
    hipMemsetAsync(degI, 0, (size_t)(SK + 3 * N) * sizeof(int), stream);
    k_hist<<<(EI + B - 1) / B, B, 0, stream>>>(intra_dst, degI, EI, 1);
    k_hist<<<(EG + B - 1) / B, B, 0, stream>>>(glob_dst, degG, EG, 1);
    k_hist<<<(SK + B - 1) / B, B, 0, stream>>>(node_ids, degN, SK, 1);
    k_hist<<<(S + B - 1) / B, B, 0, stream>>>(node_ids, degR, S, 16);
    k_scan4<<<4, 1024, 0, stream>>>(degI, startI, SK, degG, startG, N,
                                    degN, startN, N, degR, startR, N);
    hipMemsetAsync(degI, 0, (size_t)(SK + 3 * N) * sizeof(int), stream);
    k_fill_edges<<<(EI + B - 1) / B, B, 0, stream>>>(intra_dst, intra_src,
            bond_ids_intra, startI, degI, slotI, EI);
    k_fill_edges<<<(EG + B - 1) / B, B, 0, stream>>>(glob_dst, glob_src,
            bond_ids_global, startG, degG, slotG, EG);
    k_fill<<<(SK + B - 1) / B, B, 0, stream>>>(node_ids, startN, degN, slotN, SK, 1);
    k_fill<<<(S + B - 1) / B, B, 0, stream>>>(node_ids, startR, degR, slotR, S, 16);

    // ---- init ----
    k_vf<<<(SK + B - 1) / B, B, 0, stream>>>(node_ids, vf, SK);
    k_init_h<<<gwSK, B, 0, stream>>>(atom_table, role_table, atom_ids, vf, hA, SK);

    ushort_t* hcur = hA;
    ushort_t* zb   = hB;
    auto WB = [&](int fam, int l) { return wbuf + ((size_t)(fam * L + l)) * 16384; };

    for (int l = 0; l < L; ++l) {
        const size_t lb = (size_t)l * HD;
        // 1) zb = hcur + intra-GINE agg
        k_gine_z<<<gwSK, B, 0, stream>>>(hcur, bond_table, startI, slotI, zb, SK);
        // 2) hmid = relu(zb @ lW1^T + lb1)
        k_gemm1<<<ggSK, B, 0, stream>>>(zb, WB(0, l), lb1 + lb, hmid, SK, 1);
        // 3) nmean = seg_mean(hcur, node CSR)
        k_segmean<<<gwN, B, 0, stream>>>(hcur, startN, slotN, nmean, N);
        // 4) nz = nmean + global-GINE agg
        k_gine_z<<<gwN, B, 0, stream>>>(nmean, bond_table, startG, slotG, nz, N);
        // 5) nmid = relu(nz @ gW1^T + gb1)
        k_gemm1<<<ggN, B, 0, stream>>>(nz, WB(2, l), gb1 + lb, nmid, N, 1);
        // 6) h2 = nmid @ (gW2*gbn_g)^T + (gb2*gbn_g + gbn_b)
        k_gemm1<<<ggN, B, 0, stream>>>(nmid, WB(3, l), b2g + lb, h2, N, 0);
        // 7) rootm = root seg_mean(hcur)
        k_segmean<<<gwN, B, 0, stream>>>(hcur, startR, slotR, rootm, N);
        // 8) fused 4-GEMM tail -> zb
        k_gemm_fused<<<ggSK, B, 0, stream>>>(hmid, hcur, rootm, h2, node_ids, vf,
                WB(1, l), WB(4, l), WB(5, l), WB(6, l), cb + lb, zb, SK);
        ushort_t* tmp = hcur; hcur = zb; zb = tmp;
    }

    // final: node_embs = seg_mean(hcur); out = segment_sum(node_embs, batch)
    k_segmean<<<gwN, B, 0, stream>>>(hcur, startN, slotN, nmean, N);
    hipMemsetAsync(d_out, 0, (size_t)out_size * sizeof(float), stream);
    k_pool<<<gwN, B, 0, stream>>>(nmean, batch, (float*)d_out, N);
}

// Round 7
// 1047.414 us; speedup vs baseline: 11.8883x; 1.1072x over previous
//
#include <hip/hip_runtime.h>

typedef unsigned short ushort_t;
typedef unsigned int uint_t;
typedef __attribute__((ext_vector_type(8))) short v8s;   // 8 bf16 MFMA A/B frag
typedef __attribute__((ext_vector_type(4))) float v4f;   // MFMA C/D frag

#define HD 128
#define LSTR 136   // LDS weight row stride in shorts
#define MFMA16(a, b, c) __builtin_amdgcn_mfma_f32_16x16x32_bf16((a), (b), (c), 0, 0, 0)

__device__ __forceinline__ float b2f(ushort_t u) {
    union { uint_t i; float f; } v; v.i = ((uint_t)u) << 16; return v.f;
}
__device__ __forceinline__ ushort_t f2b(float f) {
    union { float f; uint_t i; } v; v.f = f;
    uint_t u = v.i;
    return (ushort_t)((u + 0x7FFFu + ((u >> 16) & 1u)) >> 16);
}

// ================= CSR build =================

__global__ __launch_bounds__(256) void k_hist(const int* __restrict__ ids,
        int* __restrict__ deg, int M, int stride) {
    int i = blockIdx.x * blockDim.x + threadIdx.x;
    if (i >= M) return;
    int id = ids[(size_t)i * stride];
    if (id >= 0) atomicAdd(&deg[id], 1);
}

// ---- two-level scan over the 4 degree arrays ----
// block mapping: a=0 tiles [0,T0), a=1..3 tiles of TN each
__device__ __forceinline__ void scan_map(int b, int T0, int TN, int& a, int& t) {
    if (b < T0) { a = 0; t = b; }
    else { int r = b - T0; a = 1 + r / TN; t = r % TN; }
}

__global__ __launch_bounds__(1024) void k_scan_up(
        const int* d0, const int* d1, const int* d2, const int* d3,
        int* s0, int* s1, int* s2, int* s3,
        int* __restrict__ tsum, int T0, int TN, int nSK, int nN) {
    int a, t;
    scan_map(blockIdx.x, T0, TN, a, t);
    const int* d = (a == 0) ? d0 : (a == 1) ? d1 : (a == 2) ? d2 : d3;
    int* s = (a == 0) ? s0 : (a == 1) ? s1 : (a == 2) ? s2 : s3;
    int n = (a == 0) ? nSK : nN;
    __shared__ int wsum[16];
    int tdx = threadIdx.x, lane = tdx & 63, wv = tdx >> 6;
    int i = t * 1024 + tdx;
    int v = (i < n) ? d[i] : 0;
    int x = v;
    #pragma unroll
    for (int off = 1; off < 64; off <<= 1) {
        int y = __shfl_up(x, off);
        if (lane >= off) x += y;
    }
    if (lane == 63) wsum[wv] = x;
    __syncthreads();
    int wo = 0, tot = 0;
    #pragma unroll
    for (int ww = 0; ww < 16; ++ww) {
        int sv = wsum[ww];
        if (ww < wv) wo += sv;
        tot += sv;
    }
    if (i < n) s[i] = wo + (x - v);
    if (tdx == 0) tsum[a * 128 + t] = tot;
}

__global__ __launch_bounds__(256) void k_scan_mid(
        const int* __restrict__ tsum, int* __restrict__ toff,
        int* s0, int* s1, int* s2, int* s3, int T0, int TN, int nSK, int nN) {
    int a = threadIdx.x >> 6, lane = threadIdx.x & 63;
    int T = (a == 0) ? T0 : TN;
    const int* ts = tsum + a * 128;
    int* to = toff + a * 128;
    int carry = 0;
    for (int base = 0; base < T; base += 64) {
        int idx = base + lane;
        int v = (idx < T) ? ts[idx] : 0;
        int x = v;
        #pragma unroll
        for (int off = 1; off < 64; off <<= 1) {
            int y = __shfl_up(x, off);
            if (lane >= off) x += y;
        }
        if (idx < T) to[idx] = carry + (x - v);
        carry += __shfl(x, 63);
    }
    if (lane == 0) {
        int* s = (a == 0) ? s0 : (a == 1) ? s1 : (a == 2) ? s2 : s3;
        s[(a == 0) ? nSK : nN] = carry;
    }
}

__global__ __launch_bounds__(1024) void k_scan_down(
        int* s0, int* s1, int* s2, int* s3,
        const int* __restrict__ toff, int T0, int TN, int nSK, int nN) {
    int a, t;
    scan_map(blockIdx.x, T0, TN, a, t);
    int* s = (a == 0) ? s0 : (a == 1) ? s1 : (a == 2) ? s2 : s3;
    int n = (a == 0) ? nSK : nN;
    int i = t * 1024 + threadIdx.x;
    if (i < n) s[i] += toff[a * 128 + t];
}

__global__ __launch_bounds__(256) void k_fill(const int* __restrict__ ids,
        const int* __restrict__ start, int* __restrict__ cursor,
        int* __restrict__ slots, int M, int stride) {
    int i = blockIdx.x * blockDim.x + threadIdx.x;
    if (i >= M) return;
    int id = ids[(size_t)i * stride];
    if (id < 0) return;
    int pos = start[id] + atomicAdd(&cursor[id], 1);
    slots[pos] = i * stride;
}

// edge CSR fill: slots[pos] = src | (bid << 20)
__global__ __launch_bounds__(256) void k_fill_edges(const int* __restrict__ dst,
        const int* __restrict__ src, const int* __restrict__ bids,
        const int* __restrict__ start, int* __restrict__ cursor,
        int* __restrict__ slots, int E) {
    int e = blockIdx.x * blockDim.x + threadIdx.x;
    if (e >= E) return;
    int d = dst[e];
    if (d < 0) return;
    int pos = start[d] + atomicAdd(&cursor[d], 1);
    slots[pos] = src[e] | (bids[e] << 20);
}

// ================= weight/bias prep =================

__global__ __launch_bounds__(256) void k_convert_w(
        const float* lW1, const float* lW2, const float* gW1, const float* gW2,
        const float* skipW, const float* vvW, const float* kkW,
        const float* lbn_g, const float* gbn_g,
        ushort_t* __restrict__ wbuf, int L) {
    int idx = blockIdx.x * blockDim.x + threadIdx.x;
    int total = 7 * L * 16384;
    if (idx >= total) return;
    int fam = idx / (L * 16384);
    int r = idx % (L * 16384);
    int l = r / 16384, e = r % 16384, n = e / 128;
    const float* src;
    float sc = 1.0f;
    switch (fam) {
        case 0: src = lW1; break;
        case 1: src = lW2; sc = lbn_g[l * 128 + n]; break;
        case 2: src = gW1; break;
        case 3: src = gW2; sc = gbn_g[l * 128 + n]; break;
        case 4: src = skipW; break;
        case 5: src = vvW; break;
        default: src = kkW; break;
    }
    wbuf[idx] = f2b(src[(size_t)l * 16384 + e] * sc);
}

__global__ __launch_bounds__(256) void k_bias(
        const float* lb2, const float* lbn_g, const float* lbn_b,
        const float* skipb, const float* vvb, const float* kkb,
        const float* gb2, const float* gbn_g, const float* gbn_b,
        float* __restrict__ cb, float* __restrict__ b2g, int total) {
    int i = blockIdx.x * blockDim.x + threadIdx.x;
    if (i >= total) return;
    cb[i] = lb2[i] * lbn_g[i] + lbn_b[i] + skipb[i] + vvb[i] + kkb[i];
    b2g[i] = gb2[i] * gbn_g[i] + gbn_b[i];
}

// ================= elementwise / graph kernels (bf16) =================

__global__ __launch_bounds__(256) void k_vf(const int* __restrict__ node_ids,
        float* __restrict__ vf, int SK) {
    int i = blockIdx.x * blockDim.x + threadIdx.x;
    if (i < SK) vf[i] = (node_ids[i] >= 0) ? 1.0f : 0.0f;
}

__global__ __launch_bounds__(256) void k_init_h(const float* __restrict__ at,
        const float* __restrict__ rt, const int* __restrict__ atom_ids,
        const float* __restrict__ vf, ushort_t* __restrict__ h, int SK) {
    int t = blockIdx.x * blockDim.x + threadIdx.x;
    int i = t >> 6, lane = t & 63;
    if (i >= SK) return;
    float2 a = ((const float2*)(at + (size_t)atom_ids[i] * HD))[lane];
    int role = ((i & 15) == 0) ? 1 : 0;
    float2 r = ((const float2*)(rt + (size_t)role * HD))[lane];
    float m = vf[i];
    uint_t o = (uint_t)f2b((a.x + r.x) * m) | ((uint_t)f2b((a.y + r.y) * m) << 16);
    *(uint_t*)(h + (size_t)i * HD + lane * 2) = o;
}

// outz[w] = X[w] + sum_p relu(X[src_p] + btab[bid_p]); slots packed src|bid<<20.
// Half-wave scheme: lanes 0-31 process even slots, 32-63 odd slots; each lane
// loads 8B (uint2, 4 bf16 cols); cross-half shuffle-combine at the end.
__global__ __launch_bounds__(256) void k_gine_z(const ushort_t* __restrict__ X,
        const float* __restrict__ btab, const int* __restrict__ start,
        const int* __restrict__ slots, ushort_t* __restrict__ outz, int Nrows) {
    int w = (blockIdx.x * 256 + threadIdx.x) >> 6;
    int lane = threadIdx.x & 63;
    if (w >= Nrows) return;
    int half = lane >> 5, hl = lane & 31;
    int s0 = start[w], s1 = start[w + 1];
    float f0 = 0.f, f1 = 0.f, f2 = 0.f, f3 = 0.f;
    int p = s0 + half;
    for (; p + 6 < s1; p += 8) {
        uint_t e0 = slots[p], e1 = slots[p + 2], e2 = slots[p + 4], e3 = slots[p + 6];
        uint2 u0 = *(const uint2*)(X + (size_t)(e0 & 0xFFFFF) * HD + hl * 4);
        uint2 u1 = *(const uint2*)(X + (size_t)(e1 & 0xFFFFF) * HD + hl * 4);
        uint2 u2 = *(const uint2*)(X + (size_t)(e2 & 0xFFFFF) * HD + hl * 4);
        uint2 u3 = *(const uint2*)(X + (size_t)(e3 & 0xFFFFF) * HD + hl * 4);
        float4 q0 = *(const float4*)(btab + (size_t)(e0 >> 20) * HD + hl * 4);
        float4 q1 = *(const float4*)(btab + (size_t)(e1 >> 20) * HD + hl * 4);
        float4 q2 = *(const float4*)(btab + (size_t)(e2 >> 20) * HD + hl * 4);
        float4 q3 = *(const float4*)(btab + (size_t)(e3 >> 20) * HD + hl * 4);
        f0 += fmaxf(b2f((ushort_t)(u0.x & 0xFFFF)) + q0.x, 0.f)
            + fmaxf(b2f((ushort_t)(u1.x & 0xFFFF)) + q1.x, 0.f)
            + fmaxf(b2f((ushort_t)(u2.x & 0xFFFF)) + q2.x, 0.f)
            + fmaxf(b2f((ushort_t)(u3.x & 0xFFFF)) + q3.x, 0.f);
        f1 += fmaxf(b2f((ushort_t)(u0.x >> 16)) + q0.y, 0.f)
            + fmaxf(b2f((ushort_t)(u1.x >> 16)) + q1.y, 0.f)
            + fmaxf(b2f((ushort_t)(u2.x >> 16)) + q2.y, 0.f)
            + fmaxf(b2f((ushort_t)(u3.x >> 16)) + q3.y, 0.f);
        f2 += fmaxf(b2f((ushort_t)(u0.y & 0xFFFF)) + q0.z, 0.f)
            + fmaxf(b2f((ushort_t)(u1.y & 0xFFFF)) + q1.z, 0.f)
            + fmaxf(b2f((ushort_t)(u2.y & 0xFFFF)) + q2.z, 0.f)
            + fmaxf(b2f((ushort_t)(u3.y & 0xFFFF)) + q3.z, 0.f);
        f3 += fmaxf(b2f((ushort_t)(u0.y >> 16)) + q0.w, 0.f)
            + fmaxf(b2f((ushort_t)(u1.y >> 16)) + q1.w, 0.f)
            + fmaxf(b2f((ushort_t)(u2.y >> 16)) + q2.w, 0.f)
            + fmaxf(b2f((ushort_t)(u3.y >> 16)) + q3.w, 0.f);
    }
    for (; p < s1; p += 2) {
        uint_t e = slots[p];
        uint2 u = *(const uint2*)(X + (size_t)(e & 0xFFFFF) * HD + hl * 4);
        float4 q = *(const float4*)(btab + (size_t)(e >> 20) * HD + hl * 4);
        f0 += fmaxf(b2f((ushort_t)(u.x & 0xFFFF)) + q.x, 0.f);
        f1 += fmaxf(b2f((ushort_t)(u.x >> 16)) + q.y, 0.f);
        f2 += fmaxf(b2f((ushort_t)(u.y & 0xFFFF)) + q.z, 0.f);
        f3 += fmaxf(b2f((ushort_t)(u.y >> 16)) + q.w, 0.f);
    }
    f0 += __shfl(f0, hl + 32);
    f1 += __shfl(f1, hl + 32);
    f2 += __shfl(f2, hl + 32);
    f3 += __shfl(f3, hl + 32);
    if (half == 0) {
        uint2 xu = *(const uint2*)(X + (size_t)w * HD + hl * 4);
        f0 += b2f((ushort_t)(xu.x & 0xFFFF));
        f1 += b2f((ushort_t)(xu.x >> 16));
        f2 += b2f((ushort_t)(xu.y & 0xFFFF));
        f3 += b2f((ushort_t)(xu.y >> 16));
        uint2 o;
        o.x = (uint_t)f2b(f0) | ((uint_t)f2b(f1) << 16);
        o.y = (uint_t)f2b(f2) | ((uint_t)f2b(f3) << 16);
        *(uint2*)(outz + (size_t)w * HD + hl * 4) = o;
    }
}

// out[w] = mean of X rows listed in slots (half-wave, 8B loads)
__global__ __launch_bounds__(256) void k_segmean(const ushort_t* __restrict__ X,
        const int* __restrict__ start, const int* __restrict__ slots,
        ushort_t* __restrict__ out, int Nrows) {
    int w = (blockIdx.x * 256 + threadIdx.x) >> 6;
    int lane = threadIdx.x & 63;
    if (w >= Nrows) return;
    int half = lane >> 5, hl = lane & 31;
    int s0 = start[w], s1 = start[w + 1];
    float inv = 1.0f / fmaxf((float)(s1 - s0), 1.0f);
    float f0 = 0.f, f1 = 0.f, f2 = 0.f, f3 = 0.f;
    int p = s0 + half;
    for (; p + 6 < s1; p += 8) {
        int r0 = slots[p], r1 = slots[p + 2], r2 = slots[p + 4], r3 = slots[p + 6];
        uint2 u0 = *(const uint2*)(X + (size_t)r0 * HD + hl * 4);
        uint2 u1 = *(const uint2*)(X + (size_t)r1 * HD + hl * 4);
        uint2 u2 = *(const uint2*)(X + (size_t)r2 * HD + hl * 4);
        uint2 u3 = *(const uint2*)(X + (size_t)r3 * HD + hl * 4);
        f0 += b2f((ushort_t)(u0.x & 0xFFFF)) + b2f((ushort_t)(u1.x & 0xFFFF))
            + b2f((ushort_t)(u2.x & 0xFFFF)) + b2f((ushort_t)(u3.x & 0xFFFF));
        f1 += b2f((ushort_t)(u0.x >> 16)) + b2f((ushort_t)(u1.x >> 16))
            + b2f((ushort_t)(u2.x >> 16)) + b2f((ushort_t)(u3.x >> 16));
        f2 += b2f((ushort_t)(u0.y & 0xFFFF)) + b2f((ushort_t)(u1.y & 0xFFFF))
            + b2f((ushort_t)(u2.y & 0xFFFF)) + b2f((ushort_t)(u3.y & 0xFFFF));
        f3 += b2f((ushort_t)(u0.y >> 16)) + b2f((ushort_t)(u1.y >> 16))
            + b2f((ushort_t)(u2.y >> 16)) + b2f((ushort_t)(u3.y >> 16));
    }
    for (; p < s1; p += 2) {
        uint2 u = *(const uint2*)(X + (size_t)slots[p] * HD + hl * 4);
        f0 += b2f((ushort_t)(u.x & 0xFFFF));
        f1 += b2f((ushort_t)(u.x >> 16));
        f2 += b2f((ushort_t)(u.y & 0xFFFF));
        f3 += b2f((ushort_t)(u.y >> 16));
    }
    f0 += __shfl(f0, hl + 32);
    f1 += __shfl(f1, hl + 32);
    f2 += __shfl(f2, hl + 32);
    f3 += __shfl(f3, hl + 32);
    if (half == 0) {
        uint2 o;
        o.x = (uint_t)f2b(f0 * inv) | ((uint_t)f2b(f1 * inv) << 16);
        o.y = (uint_t)f2b(f2 * inv) | ((uint_t)f2b(f3 * inv) << 16);
        *(uint2*)(out + (size_t)w * HD + hl * 4) = o;
    }
}

__global__ __launch_bounds__(256) void k_pool(const ushort_t* __restrict__ xsum,
        const int* __restrict__ batch, float* __restrict__ out, int N) {
    int t = blockIdx.x * blockDim.x + threadIdx.x;
    int n = t >> 6, lane = t & 63;
    if (n >= N) return;
    int g = batch[n];
    uint_t u = *(const uint_t*)(xsum + (size_t)n * HD + lane * 2);
    float* o = out + (size_t)g * HD + lane * 2;
    atomicAdd(o + 0, b2f((ushort_t)(u & 0xFFFF)));
    atomicAdd(o + 1, b2f((ushort_t)(u >> 16)));
}

// ---- shared helper: stage one 128x128 bf16 weight into padded LDS ----
__device__ __forceinline__ void stage_w(ushort_t* Wl, const ushort_t* Wb, int t) {
    #pragma unroll
    for (int it = 0; it < 8; ++it) {
        int idx = it * 256 + t;
        uint4 v = *(const uint4*)(Wb + (size_t)idx * 8);
        int row = idx >> 4, col = (idx & 15) * 8;
        *(uint4*)&Wl[row * LSTR + col] = v;
    }
}

// ================= GEMM: C = maybe_relu(A @ W^T + bias) =================
__global__ __launch_bounds__(256) void k_gemm1(const ushort_t* __restrict__ A,
        const ushort_t* __restrict__ Wb, const float* __restrict__ bias,
        ushort_t* __restrict__ C, int M, int relu_flag) {
    __shared__ ushort_t Wl[128 * LSTR];
    const int t = threadIdx.x;
    stage_w(Wl, Wb, t);
    int lane = t & 63, wave = t >> 6;
    int m = lane & 15, quad = lane >> 4;
    int row = blockIdx.x * 64 + wave * 16 + m;
    int ar = row < M ? row : M - 1;
    const v8s* Ar = (const v8s*)(A + (size_t)ar * HD);
    v8s bfrag[4];
    #pragma unroll
    for (int c = 0; c < 4; ++c) bfrag[c] = Ar[c * 4 + quad];
    __syncthreads();
    v4f acc[8];
    #pragma unroll
    for (int nt = 0; nt < 8; ++nt) acc[nt] = (v4f){0.f, 0.f, 0.f, 0.f};
    #pragma unroll
    for (int nt = 0; nt < 8; ++nt) {
        #pragma unroll
        for (int c = 0; c < 4; ++c) {
            v8s wf = *(const v8s*)&Wl[(nt * 16 + m) * LSTR + c * 32 + quad * 8];
            acc[nt] = MFMA16(wf, bfrag[c], acc[nt]);
        }
    }
    if (row < M) {
        ushort_t* Cr = C + (size_t)row * HD;
        #pragma unroll
        for (int nt = 0; nt < 8; ++nt) {
            int col = nt * 16 + quad * 4;
            float4 b = *(const float4*)(bias + col);
            float v0 = acc[nt][0] + b.x, v1 = acc[nt][1] + b.y;
            float v2 = acc[nt][2] + b.z, v3 = acc[nt][3] + b.w;
            if (relu_flag) {
                v0 = fmaxf(v0, 0.f); v1 = fmaxf(v1, 0.f);
                v2 = fmaxf(v2, 0.f); v3 = fmaxf(v3, 0.f);
            }
            uint2 o;
            o.x = (uint_t)f2b(v0) | ((uint_t)f2b(v1) << 16);
            o.y = (uint_t)f2b(v2) | ((uint_t)f2b(v3) << 16);
            *(uint2*)(Cr + col) = o;
        }
    }
}

// ================= fused 4-GEMM tail =================
__global__ __launch_bounds__(256) void k_gemm_fused(
        const ushort_t* __restrict__ hmid, const ushort_t* __restrict__ h,
        const ushort_t* __restrict__ rootm, const ushort_t* __restrict__ h2,
        const int* __restrict__ node_ids, const float* __restrict__ vf,
        const ushort_t* __restrict__ W2g, const ushort_t* __restrict__ Wsk,
        const ushort_t* __restrict__ Wvv, const ushort_t* __restrict__ Wkk,
        const float* __restrict__ cb, ushort_t* __restrict__ hout, int M) {
    __shared__ ushort_t Wl[128 * LSTR];
    const int t = threadIdx.x;
    int lane = t & 63, wave = t >> 6;
    int m = lane & 15, quad = lane >> 4;
    int row = blockIdx.x * 64 + wave * 16 + m;
    int nid = node_ids[row];
    int nc = nid > 0 ? nid : 0;
    const ushort_t* Asrc[4];
    Asrc[0] = hmid + (size_t)row * HD;
    Asrc[1] = h + (size_t)row * HD;
    Asrc[2] = rootm + (size_t)nc * HD;
    Asrc[3] = h + (size_t)(row & ~15) * HD;
    const ushort_t* Ws[4] = {W2g, Wsk, Wvv, Wkk};
    v4f acc[8];
    #pragma unroll
    for (int nt = 0; nt < 8; ++nt) acc[nt] = (v4f){0.f, 0.f, 0.f, 0.f};
    for (int ph = 0; ph < 4; ++ph) {
        if (ph) __syncthreads();
        stage_w(Wl, Ws[ph], t);
        const v8s* Ar = (const v8s*)Asrc[ph];
        v8s bfrag[4];
        #pragma unroll
        for (int c = 0; c < 4; ++c) bfrag[c] = Ar[c * 4 + quad];
        __syncthreads();
        #pragma unroll
        for (int nt = 0; nt < 8; ++nt) {
            #pragma unroll
            for (int c = 0; c < 4; ++c) {
                v8s wf = *(const v8s*)&Wl[(nt * 16 + m) * LSTR + c * 32 + quad * 8];
                acc[nt] = MFMA16(wf, bfrag[c], acc[nt]);
            }
        }
    }
    float vfm = vf[row];
    const ushort_t* h2r = h2 + (size_t)nc * HD;
    ushort_t* Cr = hout + (size_t)row * HD;
    #pragma unroll
    for (int nt = 0; nt < 8; ++nt) {
        int col = nt * 16 + quad * 4;
        float4 b = *(const float4*)(cb + col);
        uint2 hh = *(const uint2*)(h2r + col);
        float v0 = acc[nt][0] + b.x + b2f((ushort_t)(hh.x & 0xFFFF));
        float v1 = acc[nt][1] + b.y + b2f((ushort_t)(hh.x >> 16));
        float v2 = acc[nt][2] + b.z + b2f((ushort_t)(hh.y & 0xFFFF));
        float v3 = acc[nt][3] + b.w + b2f((ushort_t)(hh.y >> 16));
        v0 = fmaxf(v0, 0.f) * vfm; v1 = fmaxf(v1, 0.f) * vfm;
        v2 = fmaxf(v2, 0.f) * vfm; v3 = fmaxf(v3, 0.f) * vfm;
        uint2 o;
        o.x = (uint_t)f2b(v0) | ((uint_t)f2b(v1) << 16);
        o.y = (uint_t)f2b(v2) | ((uint_t)f2b(v3) << 16);
        *(uint2*)(Cr + col) = o;
    }
}

// ================= launcher =================

extern "C" void kernel_launch(void* const* d_in, const int* in_sizes, int n_in,
                              void* d_out, int out_size, void* d_ws, size_t ws_size,
                              hipStream_t stream) {
    (void)n_in; (void)ws_size;
    const float* atom_table = (const float*)d_in[0];
    const float* bond_table = (const float*)d_in[1];
    const float* role_table = (const float*)d_in[2];
    const float* lW1 = (const float*)d_in[3];
    const float* lb1 = (const float*)d_in[4];
    const float* lW2 = (const float*)d_in[5];
    const float* lb2 = (const float*)d_in[6];
    const float* gW1 = (const float*)d_in[7];
    const float* gb1 = (const float*)d_in[8];
    const float* gW2 = (const float*)d_in[9];
    const float* gb2 = (const float*)d_in[10];
    const float* lbn_g = (const float*)d_in[11];
    const float* lbn_b = (const float*)d_in[12];
    const float* gbn_g = (const float*)d_in[13];
    const float* gbn_b = (const float*)d_in[14];
    const float* skipW = (const float*)d_in[15];
    const float* skipb = (const float*)d_in[16];
    const float* vvW = (const float*)d_in[17];
    const float* vvb = (const float*)d_in[18];
    const float* kkW = (const float*)d_in[19];
    const float* kkb = (const float*)d_in[20];
    const int* atom_ids = (const int*)d_in[21];
    const int* bond_ids_intra = (const int*)d_in[22];
    const int* bond_ids_global = (const int*)d_in[23];
    const int* intra_ei = (const int*)d_in[24];
    const int* node_ids = (const int*)d_in[25];
    const int* edge_index = (const int*)d_in[26];
    const int* batch = (const int*)d_in[28];

    const int SK = in_sizes[21];
    const int EI = in_sizes[22];
    const int EG = in_sizes[23];
    const int N  = in_sizes[28];
    const int L  = in_sizes[4] / HD;
    const int S  = SK / 16;

    // ---- workspace layout ----
    ushort_t* us = (ushort_t*)d_ws;
    ushort_t* hA    = us;
    ushort_t* hB    = hA + (size_t)SK * HD;
    ushort_t* hmid  = hB + (size_t)SK * HD;
    ushort_t* nmean = hmid + (size_t)SK * HD;
    ushort_t* nz    = nmean + (size_t)N * HD;
    ushort_t* nmid  = nz + (size_t)N * HD;
    ushort_t* h2    = nmid + (size_t)N * HD;
    ushort_t* rootm = h2 + (size_t)N * HD;
    ushort_t* wbuf  = rootm + (size_t)N * HD;
    float* fp = (float*)(wbuf + (size_t)7 * L * 16384);
    float* vf  = fp;
    float* cb  = vf + SK;
    float* b2g = cb + (size_t)L * 128;
    int* ip = (int*)(b2g + (size_t)L * 128);
    int* degI   = ip;
    int* degG   = degI + SK;
    int* degN   = degG + N;
    int* degR   = degN + N;
    int* startI = degR + N;
    int* startG = startI + SK + 1;
    int* startN = startG + N + 1;
    int* startR = startN + N + 1;
    int* slotI  = startR + N + 1;
    int* slotG  = slotI + EI;
    int* slotN  = slotG + EG;
    int* slotR  = slotN + SK;
    int* tsum   = slotR + S;        // 4*128
    int* toff   = tsum + 512;       // 4*128

    const int B = 256;
    const int gwSK = (SK * 64 + B - 1) / B;
    const int gwN  = (N * 64 + B - 1) / B;
    const int ggSK = (SK + 63) / 64;
    const int ggN  = (N + 63) / 64;
    const int* intra_src = intra_ei;
    const int* intra_dst = intra_ei + EI;
    const int* glob_src  = edge_index;
    const int* glob_dst  = edge_index + EG;

    // ---- weight/bias prep ----
    int wtot = 7 * L * 16384;
    k_convert_w<<<(wtot + B - 1) / B, B, 0, stream>>>(lW1, lW2, gW1, gW2, skipW,
            vvW, kkW, lbn_g, gbn_g, wbuf, L);
    k_bias<<<(L * 128 + B - 1) / B, B, 0, stream>>>(lb2, lbn_g, lbn_b, skipb, vvb,
            kkb, gb2, gbn_g, gbn_b, cb, b2g, L * 128);

    // ---- CSR build ----
    hipMemsetAsync(degI, 0, (size_t)(SK + 3 * N) * sizeof(int), stream);
    k_hist<<<(EI + B - 1) / B, B, 0, stream>>>(intra_dst, degI, EI, 1);
    k_hist<<<(EG + B - 1) / B, B, 0, stream>>>(glob_dst, degG, EG, 1);
    k_hist<<<(SK + B - 1) / B, B, 0, stream>>>(node_ids, degN, SK, 1);
    k_hist<<<(S + B - 1) / B, B, 0, stream>>>(node_ids, degR, S, 16);
    const int T0 = (SK + 1023) / 1024, TN = (N + 1023) / 1024;
    const int nsb = T0 + 3 * TN;
    k_scan_up<<<nsb, 1024, 0, stream>>>(degI, degG, degN, degR,
            startI, startG, startN, startR, tsum, T0, TN, SK, N);
    k_scan_mid<<<1, 256, 0, stream>>>(tsum, toff, startI, startG, startN, startR,
            T0, TN, SK, N);
    k_scan_down<<<nsb, 1024, 0, stream>>>(startI, startG, startN, startR,
            toff, T0, TN, SK, N);
    hipMemsetAsync(degI, 0, (size_t)(SK + 3 * N) * sizeof(int), stream);
    k_fill_edges<<<(EI + B - 1) / B, B, 0, stream>>>(intra_dst, intra_src,
            bond_ids_intra, startI, degI, slotI, EI);
    k_fill_edges<<<(EG + B - 1) / B, B, 0, stream>>>(glob_dst, glob_src,
            bond_ids_global, startG, degG, slotG, EG);
    k_fill<<<(SK + B - 1) / B, B, 0, stream>>>(node_ids, startN, degN, slotN, SK, 1);
    k_fill<<<(S + B - 1) / B, B, 0, stream>>>(node_ids, startR, degR, slotR, S, 16);

    // ---- init ----
    k_vf<<<(SK + B - 1) / B, B, 0, stream>>>(node_ids, vf, SK);
    k_init_h<<<gwSK, B, 0, stream>>>(atom_table, role_table, atom_ids, vf, hA, SK);

    ushort_t* hcur = hA;
    ushort_t* zb   = hB;
    auto WB = [&](int fam, int l) { return wbuf + ((size_t)(fam * L + l)) * 16384; };

    for (int l = 0; l < L; ++l) {
        const size_t lb = (size_t)l * HD;
        // 1) zb = hcur + intra-GINE agg
        k_gine_z<<<gwSK, B, 0, stream>>>(hcur, bond_table, startI, slotI, zb, SK);
        // 2) hmid = relu(zb @ lW1^T + lb1)
        k_gemm1<<<ggSK, B, 0, stream>>>(zb, WB(0, l), lb1 + lb, hmid, SK, 1);
        // 3) nmean = seg_mean(hcur, node CSR)
        k_segmean<<<gwN, B, 0, stream>>>(hcur, startN, slotN, nmean, N);
        // 4) nz = nmean + global-GINE agg
        k_gine_z<<<gwN, B, 0, stream>>>(nmean, bond_table, startG, slotG, nz, N);
        // 5) nmid = relu(nz @ gW1^T + gb1)
        k_gemm1<<<ggN, B, 0, stream>>>(nz, WB(2, l), gb1 + lb, nmid, N, 1);
        // 6) h2 = nmid @ (gW2*gbn_g)^T + (gb2*gbn_g + gbn_b)
        k_gemm1<<<ggN, B, 0, stream>>>(nmid, WB(3, l), b2g + lb, h2, N, 0);
        // 7) rootm = root seg_mean(hcur)
        k_segmean<<<gwN, B, 0, stream>>>(hcur, startR, slotR, rootm, N);
        // 8) fused 4-GEMM tail -> zb
        k_gemm_fused<<<ggSK, B, 0, stream>>>(hmid, hcur, rootm, h2, node_ids, vf,
                WB(1, l), WB(4, l), WB(5, l), WB(6, l), cb + lb, zb, SK);
        ushort_t* tmp = hcur; hcur = zb; zb = tmp;
    }

    // final: node_embs = seg_mean(hcur); out = segment_sum(node_embs, batch)
    k_segmean<<<gwN, B, 0, stream>>>(hcur, startN, slotN, nmean, N);
    hipMemsetAsync(d_out, 0, (size_t)out_size * sizeof(float), stream);
    k_pool<<<gwN, B, 0, stream>>>(nmean, batch, (float*)d_out, N);
}